// Round 3
// baseline (645.590 us; speedup 1.0000x reference)
//
#include <hip/hip_runtime.h>

#define EPSV 1e-5f

constexpr int kB = 16, kC = 3, kT = 256, kV = 25;
constexpr int kMID = 48, kNB = 4, kOUT = 192, kN = 48;
constexpr int kS  = kB * kT * kV;   // 102400 sites (b,t,v)
constexpr int kTV = kT * kV;        // 6400

// ---------------- Phase A: recompute chain ----------------
// Each stage recomputes layers 0..L from x (cheap: <=2040 FMA/site), applies BN
// with already-finalized global stats of earlier layers, and reduces ONLY its
// own layer's (sum, sumsq). No activation tensors ever hit HBM.

template<int NO>
__device__ inline void stat_reduce(const float* y, float* statl,
                                   float* out_stats, int tid)
{
  #pragma unroll
  for (int o = 0; o < NO; o++) {
    float s1 = y[o], s2 = y[o] * y[o];
    #pragma unroll
    for (int d = 32; d > 0; d >>= 1) { s1 += __shfl_xor(s1, d); s2 += __shfl_xor(s2, d); }
    if ((tid & 63) == 0) { atomicAdd(&statl[2 * o], s1); atomicAdd(&statl[2 * o + 1], s2); }
  }
  __syncthreads();
  for (int j = tid; j < 2 * NO; j += 256) atomicAdd(&out_stats[j], statl[j]);
}

template<int DEPTH>
__global__ __launch_bounds__(256) void chain_kernel(
    const float* __restrict__ x,
    const float* __restrict__ fw0, const float* __restrict__ fb0,
    const float* __restrict__ fg0, const float* __restrict__ fbe0,
    const float* __restrict__ fw1, const float* __restrict__ fb1,
    const float* __restrict__ fg1, const float* __restrict__ fbe1,
    const float* __restrict__ fw2, const float* __restrict__ fb2,
    const float* __restrict__ fg2, const float* __restrict__ fbe2,
    const float* __restrict__ fw3, const float* __restrict__ fb3,
    const float* __restrict__ fg3, const float* __restrict__ fbe3,
    const float* __restrict__ ST,   // st0[20] st1[200] st2[20] st3[2]
    float* __restrict__ out_stats,  // this stage's raw-output stats
    float* __restrict__ hp)         // DEPTH==5 only: pooled sums per (b,v)
{
  __shared__ __align__(16) float w0p[40];    // [o][4]: w,w,w,bias
  __shared__ __align__(16) float w1p[1200];  // [o][12]: 10 w, bias, pad
  __shared__ __align__(16) float w2p[1000];  // [o][100]
  __shared__ __align__(16) float w3p[12];    // 10 w, bias, pad
  __shared__ float b2s[10];
  __shared__ float sc0[10], sh0[10], sc1[100], sh1[100], sc2[10], sh2[10];
  __shared__ float sc3s, sh3s;
  __shared__ float statl[200];
  __shared__ float poolp[25];
  const int tid = threadIdx.x;

  for (int j = tid; j < 40; j += 256) {
    int o = j >> 2, c = j & 3;
    w0p[j] = (c < 3) ? fw0[o * 3 + c] : fb0[o];
  }
  if constexpr (DEPTH >= 2) {
    for (int j = tid; j < 1200; j += 256) {
      int o = j / 12, c = j - o * 12;
      w1p[j] = (c < 10) ? fw1[o * 10 + c] : (c == 10 ? fb1[o] : 0.f);
    }
    if (tid < 10) {
      float m = ST[2 * tid] * (1.f / kS);
      float vr = ST[2 * tid + 1] * (1.f / kS) - m * m;
      float s = fg0[tid] * rsqrtf(vr + EPSV);
      sc0[tid] = s; sh0[tid] = fbe0[tid] - m * s;
    }
  }
  if constexpr (DEPTH >= 3) {
    for (int j = tid; j < 1000; j += 256) w2p[j] = fw2[j];
    if (tid < 10) b2s[tid] = fb2[tid];
    if (tid < 100) {
      const float* st1 = ST + 20;
      float m = st1[2 * tid] * (1.f / kS);
      float vr = st1[2 * tid + 1] * (1.f / kS) - m * m;
      float s = fg1[tid] * rsqrtf(vr + EPSV);
      sc1[tid] = s; sh1[tid] = fbe1[tid] - m * s;
    }
  }
  if constexpr (DEPTH >= 4) {
    if (tid < 12) w3p[tid] = (tid < 10) ? fw3[tid] : (tid == 10 ? fb3[0] : 0.f);
    if (tid < 10) {
      const float* st2 = ST + 220;
      float m = st2[2 * tid] * (1.f / kS);
      float vr = st2[2 * tid + 1] * (1.f / kS) - m * m;
      float s = fg2[tid] * rsqrtf(vr + EPSV);
      sc2[tid] = s; sh2[tid] = fbe2[tid] - m * s;
    }
  }
  if constexpr (DEPTH >= 5) {
    if (tid == 0) {
      const float* st3 = ST + 240;
      float m = st3[0] * (1.f / kS);
      float vr = st3[1] * (1.f / kS) - m * m;
      float s = fg3[0] * rsqrtf(vr + EPSV);
      sc3s = s; sh3s = fbe3[0] - m * s;
    }
    if (tid < 25) poolp[tid] = 0.f;
  }
  if constexpr (DEPTH <= 4) {
    constexpr int NO = (DEPTH == 1) ? 10 : (DEPTH == 2) ? 100 : (DEPTH == 3) ? 10 : 1;
    for (int j = tid; j < 2 * NO; j += 256) statl[j] = 0.f;
  }
  __syncthreads();

  const int s = blockIdx.x * 256 + tid;
  const int b = s / kTV, r = s - b * kTV;

  // layer 0: 3 -> 10
  const float xv0 = x[(b * 3 + 0) * kTV + r];
  const float xv1 = x[(b * 3 + 1) * kTV + r];
  const float xv2 = x[(b * 3 + 2) * kTV + r];
  float h0[10];
  #pragma unroll
  for (int o = 0; o < 10; o++) {
    const float4 w = *(const float4*)&w0p[o * 4];
    h0[o] = fmaf(xv0, w.x, fmaf(xv1, w.y, fmaf(xv2, w.z, w.w)));
  }
  if constexpr (DEPTH == 1) { stat_reduce<10>(h0, statl, out_stats, tid); return; }

  // bn0 + relu, layer 1: 10 -> 100
  #pragma unroll
  for (int o = 0; o < 10; o++) h0[o] = fmaxf(fmaf(h0[o], sc0[o], sh0[o]), 0.f);
  float y1[100];
  #pragma unroll
  for (int o = 0; o < 100; o++) {
    const float4 wa = *(const float4*)&w1p[o * 12];
    const float4 wb = *(const float4*)&w1p[o * 12 + 4];
    const float4 wc = *(const float4*)&w1p[o * 12 + 8];
    float a = wc.z;  // bias
    a = fmaf(h0[0], wa.x, a); a = fmaf(h0[1], wa.y, a);
    a = fmaf(h0[2], wa.z, a); a = fmaf(h0[3], wa.w, a);
    a = fmaf(h0[4], wb.x, a); a = fmaf(h0[5], wb.y, a);
    a = fmaf(h0[6], wb.z, a); a = fmaf(h0[7], wb.w, a);
    a = fmaf(h0[8], wc.x, a); a = fmaf(h0[9], wc.y, a);
    y1[o] = a;
  }
  if constexpr (DEPTH == 2) { stat_reduce<100>(y1, statl, out_stats, tid); return; }

  // bn1 + relu, layer 2: 100 -> 10
  #pragma unroll
  for (int o = 0; o < 100; o++) y1[o] = fmaxf(fmaf(y1[o], sc1[o], sh1[o]), 0.f);
  float acc[10];
  #pragma unroll
  for (int o = 0; o < 10; o++) acc[o] = b2s[o];
  #pragma unroll
  for (int cc = 0; cc < 100; cc += 4) {
    const float hv0 = y1[cc], hv1 = y1[cc + 1], hv2 = y1[cc + 2], hv3 = y1[cc + 3];
    #pragma unroll
    for (int o = 0; o < 10; o++) {
      const float4 w = *(const float4*)&w2p[o * 100 + cc];
      acc[o] = fmaf(hv0, w.x, fmaf(hv1, w.y, fmaf(hv2, w.z, fmaf(hv3, w.w, acc[o]))));
    }
  }
  if constexpr (DEPTH == 3) { stat_reduce<10>(acc, statl, out_stats, tid); return; }

  // bn2 + relu, layer 3: 10 -> 1
  #pragma unroll
  for (int o = 0; o < 10; o++) acc[o] = fmaxf(fmaf(acc[o], sc2[o], sh2[o]), 0.f);
  const float4 wa = *(const float4*)&w3p[0];
  const float4 wb = *(const float4*)&w3p[4];
  const float4 wc = *(const float4*)&w3p[8];
  float y3 = wc.z;  // bias
  y3 = fmaf(acc[0], wa.x, y3); y3 = fmaf(acc[1], wa.y, y3);
  y3 = fmaf(acc[2], wa.z, y3); y3 = fmaf(acc[3], wa.w, y3);
  y3 = fmaf(acc[4], wb.x, y3); y3 = fmaf(acc[5], wb.y, y3);
  y3 = fmaf(acc[6], wb.z, y3); y3 = fmaf(acc[7], wb.w, y3);
  y3 = fmaf(acc[8], wc.x, y3); y3 = fmaf(acc[9], wc.y, y3);
  if constexpr (DEPTH == 4) { stat_reduce<1>(&y3, statl, out_stats, tid); return; }

  // DEPTH==5: bn3 + relu + T-pool partial sums
  if constexpr (DEPTH == 5) {
    float h3 = fmaxf(fmaf(y3, sc3s, sh3s), 0.f);
    const int v = r % 25;
    atomicAdd(&poolp[v], h3);
    __syncthreads();
    if (tid < 25) atomicAdd(&hp[b * 25 + tid], poolp[tid]);
  }
}

// tiny FC head: hp sums (16,25) -> 100 -> 192 with per-batch BN
__global__ __launch_bounds__(256) void head_kernel(
    const float* __restrict__ hp,
    const float* __restrict__ cw0, const float* __restrict__ cb0,
    const float* __restrict__ cg0, const float* __restrict__ cbe0,
    const float* __restrict__ cw1, const float* __restrict__ cb1,
    const float* __restrict__ cg1, const float* __restrict__ cbe1,
    float* __restrict__ xg, float* __restrict__ xgT)
{
  __shared__ float hpl[400];
  __shared__ float y1[100 * 16];
  __shared__ float y2l[192 * 16];
  const int tid = threadIdx.x;
  for (int j = tid; j < 400; j += 256) hpl[j] = hp[j] * (1.f / kT);
  __syncthreads();
  for (int j = tid; j < 1600; j += 256) {
    int o = j >> 4, b = j & 15;
    float acc = cb0[o];
    for (int v = 0; v < 25; v++) acc = fmaf(hpl[b * 25 + v], cw0[o * 25 + v], acc);
    y1[o * 16 + b] = acc;
  }
  __syncthreads();
  if (tid < 100) {
    float s1 = 0.f, s2 = 0.f;
    for (int b = 0; b < 16; b++) { float val = y1[tid * 16 + b]; s1 += val; s2 += val * val; }
    float m = s1 * (1.f / 16), vr = s2 * (1.f / 16) - m * m;
    float scale = cg0[tid] * rsqrtf(vr + EPSV);
    float shift = cbe0[tid] - m * scale;
    for (int b = 0; b < 16; b++)
      y1[tid * 16 + b] = fmaxf(fmaf(y1[tid * 16 + b], scale, shift), 0.f);
  }
  __syncthreads();
  for (int j = tid; j < 3072; j += 256) {
    int o = j >> 4, b = j & 15;
    float acc = cb1[o];
    for (int c = 0; c < 100; c++) acc = fmaf(y1[c * 16 + b], cw1[o * 100 + c], acc);
    y2l[o * 16 + b] = acc;
  }
  __syncthreads();
  if (tid < 192) {
    float s1 = 0.f, s2 = 0.f;
    for (int b = 0; b < 16; b++) { float val = y2l[tid * 16 + b]; s1 += val; s2 += val * val; }
    float m = s1 * (1.f / 16), vr = s2 * (1.f / 16) - m * m;
    float scale = cg1[tid] * rsqrtf(vr + EPSV);
    float shift = cbe1[tid] - m * scale;
    for (int b = 0; b < 16; b++) {
      float r = fmaxf(fmaf(y2l[tid * 16 + b], scale, shift), 0.f);
      xg[b * 192 + tid]  = r;
      xgT[tid * 16 + b]  = r;
    }
  }
}

// ---------------- Phase B: fused dilated conv + gate + relu + Ww-dot + loss --------
__global__ __launch_bounds__(256) void conv_fuse(
    const float* __restrict__ x, const float* __restrict__ Wb,
    const float* __restrict__ bb, const float* __restrict__ Ww,
    const float* __restrict__ bw, const float* __restrict__ xg,
    float* __restrict__ out_loss)
{
  __shared__ __align__(16) float xs[25 * 264];   // [ci][8 + t], 8 zeros causal history
  __shared__ __align__(16) float wbl[75 * 48];   // [(ci*3+k)][m]
  __shared__ float wwl[25 * 193];                // Ww padded stride 193
  __shared__ float xgl[192];
  __shared__ float bbl[192];
  __shared__ float bwl[25];
  const int tid = threadIdx.x;
  const int wg = blockIdx.x;
  const int v = wg % 25, n = wg / 25;
  const int b = n / 3;

  for (int j = tid; j < 6400; j += 256) {
    int t = j / 25, ci = j - t * 25;
    xs[ci * 264 + 8 + t] = x[n * 6400 + j];
  }
  for (int j = tid; j < 200; j += 256) {
    int ci = j >> 3, q = j & 7;
    xs[ci * 264 + q] = 0.f;
  }
  for (int j = tid; j < 4800; j += 256) {
    int vv = j / 192, o = j - vv * 192;
    wwl[vv * 193 + o] = Ww[j];
  }
  for (int j = tid; j < 192; j += 256) {
    xgl[j] = xg[b * 192 + j];
    int i = j / 48, m = j - i * 48;
    bbl[j] = bb[(i * 25 + v) * 48 + m];
  }
  if (tid < 25) bwl[tid] = bw[tid];

  const int mq = tid & 3, tl = tid >> 2;
  int wwbase[4], tp_[4], vp_[4];
  #pragma unroll
  for (int tt = 0; tt < 4; tt++) {
    int flat = v * 256 + tl + 64 * tt;   // flat = v*T + t  ->  (t', v')
    tp_[tt] = flat / 25;
    vp_[tt] = flat - tp_[tt] * 25;
    wwbase[tt] = vp_[tt] * 193;
  }
  float accout[4] = {0.f, 0.f, 0.f, 0.f};

  for (int i = 0; i < 4; i++) {
    __syncthreads();
    const float* wsrc = Wb + (i * 25 + v) * 3600;
    for (int j = tid; j < 3600; j += 256) {
      int m = j / 75, q = j - m * 75;
      wbl[q * 48 + m] = wsrc[j];
    }
    __syncthreads();
    const int d = i + 1;
    float conv[12][4];
    #pragma unroll
    for (int mi = 0; mi < 12; mi++) {
      float bv = bbl[i * 48 + mq * 12 + mi];
      #pragma unroll
      for (int tt = 0; tt < 4; tt++) conv[mi][tt] = bv;
    }
    for (int ci = 0; ci < 25; ci++) {
      const float* xrow  = &xs[ci * 264 + 8 + tl];
      const float* wrow0 = &wbl[(ci * 3) * 48 + mq * 12];
      #pragma unroll
      for (int k = 0; k < 3; k++) {
        const int off = (k - 2) * d;
        const float4 wa  = *(const float4*)(wrow0 + k * 48);
        const float4 wb2 = *(const float4*)(wrow0 + k * 48 + 4);
        const float4 wc  = *(const float4*)(wrow0 + k * 48 + 8);
        const float wr[12] = {wa.x, wa.y, wa.z, wa.w,
                              wb2.x, wb2.y, wb2.z, wb2.w,
                              wc.x, wc.y, wc.z, wc.w};
        float xv[4];
        #pragma unroll
        for (int tt = 0; tt < 4; tt++) xv[tt] = xrow[64 * tt + off];
        #pragma unroll
        for (int mi = 0; mi < 12; mi++)
          #pragma unroll
          for (int tt = 0; tt < 4; tt++)
            conv[mi][tt] = fmaf(xv[tt], wr[mi], conv[mi][tt]);
      }
    }
    #pragma unroll
    for (int mi = 0; mi < 12; mi++) {
      const int o = i * 48 + mq * 12 + mi;
      const float gate = xgl[o];
      #pragma unroll
      for (int tt = 0; tt < 4; tt++) {
        float z = fmaxf(gate * conv[mi][tt], 0.f);
        accout[tt] = fmaf(z, wwl[wwbase[tt] + o], accout[tt]);
      }
    }
  }
  #pragma unroll
  for (int tt = 0; tt < 4; tt++) {
    float a = accout[tt];
    a += __shfl_xor(a, 1);
    a += __shfl_xor(a, 2);
    if (mq == 0 && tp_[tt] < 255) {
      float pf = a + bwl[vp_[tt]];
      float xn = x[n * 6400 + (tp_[tt] + 1) * 25 + vp_[tt]];
      float dd = pf - xn;
      out_loss[(n * 25 + vp_[tt]) * 255 + tp_[tt]] = dd * dd;
    }
  }
}

// ---------------- Phase C: gc max + group-lasso reg (625 blocks) ----------------
__global__ __launch_bounds__(64) void gc_reg_kernel(
    const float* __restrict__ Wb, const float* __restrict__ xgT,
    float* __restrict__ gc_out, float* __restrict__ reg_out)
{
  __shared__ float sW[576];        // [o=(i*48+m)][k]
  __shared__ float sG[192 * 17];   // [o][b], stride 17 (bank-spread)
  const int tid = threadIdx.x;
  const int v1 = blockIdx.x / 25, v2 = blockIdx.x % 25;
  for (int j = tid; j < 3072; j += 64) {
    int o = j >> 4, bq = j & 15;
    sG[o * 17 + bq] = xgT[j];
  }
  for (int p = tid; p < 192; p += 64) {
    int i = p / 48, m = p - i * 48;
    const float* src = Wb + ((i * 25 + v1) * 48 + m) * 75 + v2 * 3;
    sW[p * 3 + 0] = src[0]; sW[p * 3 + 1] = src[1]; sW[p * 3 + 2] = src[2];
  }
  __syncthreads();
  const int b = tid & 15, c = tid >> 4;   // c in 0..3 -> o-chunk
  float s0 = 0.f, s1 = 0.f, s2 = 0.f, mx = -3.0e38f;
  #pragma unroll 4
  for (int o = c * 48; o < c * 48 + 48; o++) {
    float g = sG[o * 17 + b];
    float a0 = sW[o * 3] * g, a1 = sW[o * 3 + 1] * g, a2 = sW[o * 3 + 2] * g;
    s0 = fmaf(a0, a0, s0);
    s1 = fmaf(a1, a1, s1);
    s2 = fmaf(a2, a2, s2);
    mx = fmaxf(mx, fmaxf(fmaxf(a0, a1), a2));
  }
  s0 += __shfl_xor(s0, 16); s0 += __shfl_xor(s0, 32);
  s1 += __shfl_xor(s1, 16); s1 += __shfl_xor(s1, 32);
  s2 += __shfl_xor(s2, 16); s2 += __shfl_xor(s2, 32);
  mx = fmaxf(mx, __shfl_xor(mx, 16)); mx = fmaxf(mx, __shfl_xor(mx, 32));
  float contrib = 0.f;
  if (c == 0) {
    gc_out[(b * 25 + v1) * 25 + v2] = mx;
    contrib = sqrtf(s0 + s1 + s2) + sqrtf(s0) + sqrtf(s1) + sqrtf(s2);
  }
  #pragma unroll
  for (int d = 1; d < 16; d <<= 1) contrib += __shfl_xor(contrib, d);
  if (tid == 0) atomicAdd(reg_out, 0.01f * contrib);
}

extern "C" void kernel_launch(void* const* d_in, const int* in_sizes, int n_in,
                              void* d_out, int out_size, void* d_ws, size_t ws_size,
                              hipStream_t stream)
{
  const float* x    = (const float*)d_in[0];
  const float* Wb   = (const float*)d_in[1];
  const float* bb   = (const float*)d_in[2];
  const float* fw0  = (const float*)d_in[3];
  const float* fb0  = (const float*)d_in[4];
  const float* fg0  = (const float*)d_in[5];
  const float* fbe0 = (const float*)d_in[6];
  const float* fw1  = (const float*)d_in[7];
  const float* fb1  = (const float*)d_in[8];
  const float* fg1  = (const float*)d_in[9];
  const float* fbe1 = (const float*)d_in[10];
  const float* fw2  = (const float*)d_in[11];
  const float* fb2  = (const float*)d_in[12];
  const float* fg2  = (const float*)d_in[13];
  const float* fbe2 = (const float*)d_in[14];
  const float* fw3  = (const float*)d_in[15];
  const float* fb3  = (const float*)d_in[16];
  const float* fg3  = (const float*)d_in[17];
  const float* fbe3 = (const float*)d_in[18];
  const float* cw0  = (const float*)d_in[19];
  const float* cb0  = (const float*)d_in[20];
  const float* cg0  = (const float*)d_in[21];
  const float* cbe0 = (const float*)d_in[22];
  const float* cw1  = (const float*)d_in[23];
  const float* cb1  = (const float*)d_in[24];
  const float* cg1  = (const float*)d_in[25];
  const float* cbe1 = (const float*)d_in[26];
  const float* Ww   = (const float*)d_in[27];
  const float* bw   = (const float*)d_in[28];

  float* ws  = (float*)d_ws;
  float* out = (float*)d_out;

  float* ST  = ws;            // st0[20] st1[200] st2[20] st3[2] = 242
  float* HP  = ws + 242;      // 400
  float* XG  = ws + 642;      // 3072 (b-major)
  float* XGT = XG + 3072;     // 3072 (o-major)

  hipMemsetAsync(ST, 0, 642 * sizeof(float), stream);          // stats + hp
  hipMemsetAsync(out + 316000, 0, sizeof(float), stream);      // reg scalar

  chain_kernel<1><<<400, 256, 0, stream>>>(x, fw0, fb0, fg0, fbe0, fw1, fb1, fg1, fbe1,
      fw2, fb2, fg2, fbe2, fw3, fb3, fg3, fbe3, ST, ST, nullptr);
  chain_kernel<2><<<400, 256, 0, stream>>>(x, fw0, fb0, fg0, fbe0, fw1, fb1, fg1, fbe1,
      fw2, fb2, fg2, fbe2, fw3, fb3, fg3, fbe3, ST, ST + 20, nullptr);
  chain_kernel<3><<<400, 256, 0, stream>>>(x, fw0, fb0, fg0, fbe0, fw1, fb1, fg1, fbe1,
      fw2, fb2, fg2, fbe2, fw3, fb3, fg3, fbe3, ST, ST + 220, nullptr);
  chain_kernel<4><<<400, 256, 0, stream>>>(x, fw0, fb0, fg0, fbe0, fw1, fb1, fg1, fbe1,
      fw2, fb2, fg2, fbe2, fw3, fb3, fg3, fbe3, ST, ST + 240, nullptr);
  chain_kernel<5><<<400, 256, 0, stream>>>(x, fw0, fb0, fg0, fbe0, fw1, fb1, fg1, fbe1,
      fw2, fb2, fg2, fbe2, fw3, fb3, fg3, fbe3, ST, nullptr, HP);
  head_kernel<<<1, 256, 0, stream>>>(HP, cw0, cb0, cg0, cbe0, cw1, cb1, cg1, cbe1, XG, XGT);
  conv_fuse<<<1200, 256, 0, stream>>>(x, Wb, bb, Ww, bw, XG, out);
  gc_reg_kernel<<<625, 64, 0, stream>>>(Wb, XGT, out + 306000, out + 316000);
}

// Round 4
// 299.419 us; speedup vs baseline: 2.1561x; 2.1561x over previous
//
#include <hip/hip_runtime.h>

#define EPSV 1e-5f

constexpr int kB = 16, kC = 3, kT = 256, kV = 25;
constexpr int kMID = 48, kNB = 4, kOUT = 192, kN = 48;
constexpr int kS  = kB * kT * kV;   // 102400 sites (b,t,v)
constexpr int kTV = kT * kV;        // 6400

// ---------------- Phase A: recompute chain (register-streaming) ----------------
// Each stage recomputes layers 0..L from x, applies BN with already-finalized
// stats of earlier layers, and reduces ONLY its own layer's (sum, sumsq).
// The 100-wide layer is STREAMED one channel at a time (never stored as a
// per-thread array) -> no scratch spill (R3 lesson: y1[100] cost 313 MB/dispatch
// of scratch writes, 256 VGPR, 210us/stage).

template<int NO>
__device__ __forceinline__ void stat_reduce_reg(const float (&y)[NO], float* statl,
                                                float* out_stats, int tid)
{
  #pragma unroll
  for (int o = 0; o < NO; o++) {
    float s1 = y[o], s2 = y[o] * y[o];
    #pragma unroll
    for (int d = 32; d > 0; d >>= 1) { s1 += __shfl_xor(s1, d); s2 += __shfl_xor(s2, d); }
    if ((tid & 63) == 0) { atomicAdd(&statl[2 * o], s1); atomicAdd(&statl[2 * o + 1], s2); }
  }
  __syncthreads();
  for (int j = tid; j < 2 * NO; j += 256) atomicAdd(&out_stats[j], statl[j]);
}

template<int DEPTH>
__global__ __launch_bounds__(256) void chain_kernel(
    const float* __restrict__ x,
    const float* __restrict__ fw0, const float* __restrict__ fb0,
    const float* __restrict__ fg0, const float* __restrict__ fbe0,
    const float* __restrict__ fw1, const float* __restrict__ fb1,
    const float* __restrict__ fg1, const float* __restrict__ fbe1,
    const float* __restrict__ fw2, const float* __restrict__ fb2,
    const float* __restrict__ fg2, const float* __restrict__ fbe2,
    const float* __restrict__ fw3, const float* __restrict__ fb3,
    const float* __restrict__ fg3, const float* __restrict__ fbe3,
    const float* __restrict__ ST,   // st0[20] st1[200] st2[20] st3[2]
    float* __restrict__ out_stats,  // this stage's raw-output stats
    float* __restrict__ hp)         // DEPTH==5 only: pooled sums per (b,v)
{
  __shared__ __align__(16) float w0p[40];    // [o][4]: w,w,w,bias
  __shared__ __align__(16) float w1p[1200];  // [o][12]: 10 w, bias, pad
  __shared__ __align__(16) float w2t[1200];  // [c][12]: fw2[j][c] transposed, pad
  __shared__ __align__(16) float w3p[12];    // 10 w, bias, pad
  __shared__ float b2s[10];
  __shared__ float sc0[10], sh0[10], sc1[100], sh1[100], sc2[10], sh2[10];
  __shared__ float sc3s, sh3s;
  __shared__ float statl[200];
  __shared__ float poolp[25];
  const int tid = threadIdx.x;

  for (int j = tid; j < 40; j += 256) {
    int o = j >> 2, c = j & 3;
    w0p[j] = (c < 3) ? fw0[o * 3 + c] : fb0[o];
  }
  if constexpr (DEPTH >= 2) {
    for (int j = tid; j < 1200; j += 256) {
      int o = j / 12, c = j - o * 12;
      w1p[j] = (c < 10) ? fw1[o * 10 + c] : (c == 10 ? fb1[o] : 0.f);
    }
    if (tid < 10) {
      float m = ST[2 * tid] * (1.f / kS);
      float vr = ST[2 * tid + 1] * (1.f / kS) - m * m;
      float s = fg0[tid] * rsqrtf(vr + EPSV);
      sc0[tid] = s; sh0[tid] = fbe0[tid] - m * s;
    }
  }
  if constexpr (DEPTH >= 3) {
    for (int j = tid; j < 1000; j += 256) {
      int jj = j / 100, c = j - jj * 100;
      w2t[c * 12 + jj] = fw2[j];
    }
    for (int c = tid; c < 100; c += 256) { w2t[c * 12 + 10] = 0.f; w2t[c * 12 + 11] = 0.f; }
    if (tid < 10) b2s[tid] = fb2[tid];
    if (tid < 100) {
      const float* st1 = ST + 20;
      float m = st1[2 * tid] * (1.f / kS);
      float vr = st1[2 * tid + 1] * (1.f / kS) - m * m;
      float s = fg1[tid] * rsqrtf(vr + EPSV);
      sc1[tid] = s; sh1[tid] = fbe1[tid] - m * s;
    }
  }
  if constexpr (DEPTH >= 4) {
    if (tid < 12) w3p[tid] = (tid < 10) ? fw3[tid] : (tid == 10 ? fb3[0] : 0.f);
    if (tid < 10) {
      const float* st2 = ST + 220;
      float m = st2[2 * tid] * (1.f / kS);
      float vr = st2[2 * tid + 1] * (1.f / kS) - m * m;
      float s = fg2[tid] * rsqrtf(vr + EPSV);
      sc2[tid] = s; sh2[tid] = fbe2[tid] - m * s;
    }
  }
  if constexpr (DEPTH >= 5) {
    if (tid == 0) {
      const float* st3 = ST + 240;
      float m = st3[0] * (1.f / kS);
      float vr = st3[1] * (1.f / kS) - m * m;
      float s = fg3[0] * rsqrtf(vr + EPSV);
      sc3s = s; sh3s = fbe3[0] - m * s;
    }
    if (tid < 25) poolp[tid] = 0.f;
  }
  if constexpr (DEPTH <= 4) {
    constexpr int NO = (DEPTH == 1) ? 10 : (DEPTH == 2) ? 100 : (DEPTH == 3) ? 10 : 1;
    for (int j = tid; j < 2 * NO; j += 256) statl[j] = 0.f;
  }
  __syncthreads();

  const int s = blockIdx.x * 256 + tid;
  const int b = s / kTV, r = s - b * kTV;

  // layer 0: 3 -> 10
  const float xv0 = x[(b * 3 + 0) * kTV + r];
  const float xv1 = x[(b * 3 + 1) * kTV + r];
  const float xv2 = x[(b * 3 + 2) * kTV + r];
  float h0[10];
  #pragma unroll
  for (int o = 0; o < 10; o++) {
    const float4 w = *(const float4*)&w0p[o * 4];
    h0[o] = fmaf(xv0, w.x, fmaf(xv1, w.y, fmaf(xv2, w.z, w.w)));
  }
  if constexpr (DEPTH == 1) { stat_reduce_reg<10>(h0, statl, out_stats, tid); return; }

  // bn0 + relu
  #pragma unroll
  for (int o = 0; o < 10; o++) h0[o] = fmaxf(fmaf(h0[o], sc0[o], sh0[o]), 0.f);

  if constexpr (DEPTH == 2) {
    // stream layer 1 channels: compute, reduce stats, discard
    for (int o = 0; o < 100; o++) {
      const float4 wa = *(const float4*)&w1p[o * 12];
      const float4 wb = *(const float4*)&w1p[o * 12 + 4];
      const float4 wc = *(const float4*)&w1p[o * 12 + 8];
      float a = wc.z;  // bias
      a = fmaf(h0[0], wa.x, a); a = fmaf(h0[1], wa.y, a);
      a = fmaf(h0[2], wa.z, a); a = fmaf(h0[3], wa.w, a);
      a = fmaf(h0[4], wb.x, a); a = fmaf(h0[5], wb.y, a);
      a = fmaf(h0[6], wb.z, a); a = fmaf(h0[7], wb.w, a);
      a = fmaf(h0[8], wc.x, a); a = fmaf(h0[9], wc.y, a);
      float s1 = a, s2 = a * a;
      #pragma unroll
      for (int d = 32; d > 0; d >>= 1) { s1 += __shfl_xor(s1, d); s2 += __shfl_xor(s2, d); }
      if ((tid & 63) == 0) { atomicAdd(&statl[2 * o], s1); atomicAdd(&statl[2 * o + 1], s2); }
    }
    __syncthreads();
    for (int j = tid; j < 200; j += 256) atomicAdd(&out_stats[j], statl[j]);
    return;
  }

  // DEPTH >= 3: stream layer1 -> bn1+relu -> fold into layer2 accumulation
  float acc[10];
  #pragma unroll
  for (int j = 0; j < 10; j++) acc[j] = b2s[j];
  for (int o = 0; o < 100; o++) {
    const float4 wa = *(const float4*)&w1p[o * 12];
    const float4 wb = *(const float4*)&w1p[o * 12 + 4];
    const float4 wc = *(const float4*)&w1p[o * 12 + 8];
    float a = wc.z;  // bias
    a = fmaf(h0[0], wa.x, a); a = fmaf(h0[1], wa.y, a);
    a = fmaf(h0[2], wa.z, a); a = fmaf(h0[3], wa.w, a);
    a = fmaf(h0[4], wb.x, a); a = fmaf(h0[5], wb.y, a);
    a = fmaf(h0[6], wb.z, a); a = fmaf(h0[7], wb.w, a);
    a = fmaf(h0[8], wc.x, a); a = fmaf(h0[9], wc.y, a);
    float h1 = fmaxf(fmaf(a, sc1[o], sh1[o]), 0.f);
    const float4 va = *(const float4*)&w2t[o * 12];
    const float4 vb = *(const float4*)&w2t[o * 12 + 4];
    const float4 vc = *(const float4*)&w2t[o * 12 + 8];
    acc[0] = fmaf(h1, va.x, acc[0]); acc[1] = fmaf(h1, va.y, acc[1]);
    acc[2] = fmaf(h1, va.z, acc[2]); acc[3] = fmaf(h1, va.w, acc[3]);
    acc[4] = fmaf(h1, vb.x, acc[4]); acc[5] = fmaf(h1, vb.y, acc[5]);
    acc[6] = fmaf(h1, vb.z, acc[6]); acc[7] = fmaf(h1, vb.w, acc[7]);
    acc[8] = fmaf(h1, vc.x, acc[8]); acc[9] = fmaf(h1, vc.y, acc[9]);
  }
  if constexpr (DEPTH == 3) { stat_reduce_reg<10>(acc, statl, out_stats, tid); return; }

  // bn2 + relu, layer 3: 10 -> 1
  #pragma unroll
  for (int o = 0; o < 10; o++) acc[o] = fmaxf(fmaf(acc[o], sc2[o], sh2[o]), 0.f);
  const float4 wa = *(const float4*)&w3p[0];
  const float4 wb = *(const float4*)&w3p[4];
  const float4 wc = *(const float4*)&w3p[8];
  float y3 = wc.z;  // bias
  y3 = fmaf(acc[0], wa.x, y3); y3 = fmaf(acc[1], wa.y, y3);
  y3 = fmaf(acc[2], wa.z, y3); y3 = fmaf(acc[3], wa.w, y3);
  y3 = fmaf(acc[4], wb.x, y3); y3 = fmaf(acc[5], wb.y, y3);
  y3 = fmaf(acc[6], wb.z, y3); y3 = fmaf(acc[7], wb.w, y3);
  y3 = fmaf(acc[8], wc.x, y3); y3 = fmaf(acc[9], wc.y, y3);
  if constexpr (DEPTH == 4) {
    float t1[1] = { y3 };
    stat_reduce_reg<1>(t1, statl, out_stats, tid);
    return;
  }

  // DEPTH==5: bn3 + relu + T-pool partial sums
  if constexpr (DEPTH == 5) {
    float h3 = fmaxf(fmaf(y3, sc3s, sh3s), 0.f);
    const int v = r % 25;
    atomicAdd(&poolp[v], h3);
    __syncthreads();
    if (tid < 25) atomicAdd(&hp[b * 25 + tid], poolp[tid]);
  }
}

// tiny FC head: hp sums (16,25) -> 100 -> 192 with per-batch BN
__global__ __launch_bounds__(256) void head_kernel(
    const float* __restrict__ hp,
    const float* __restrict__ cw0, const float* __restrict__ cb0,
    const float* __restrict__ cg0, const float* __restrict__ cbe0,
    const float* __restrict__ cw1, const float* __restrict__ cb1,
    const float* __restrict__ cg1, const float* __restrict__ cbe1,
    float* __restrict__ xg, float* __restrict__ xgT)
{
  __shared__ float hpl[400];
  __shared__ float y1[100 * 16];
  __shared__ float y2l[192 * 16];
  const int tid = threadIdx.x;
  for (int j = tid; j < 400; j += 256) hpl[j] = hp[j] * (1.f / kT);
  __syncthreads();
  for (int j = tid; j < 1600; j += 256) {
    int o = j >> 4, b = j & 15;
    float acc = cb0[o];
    for (int v = 0; v < 25; v++) acc = fmaf(hpl[b * 25 + v], cw0[o * 25 + v], acc);
    y1[o * 16 + b] = acc;
  }
  __syncthreads();
  if (tid < 100) {
    float s1 = 0.f, s2 = 0.f;
    for (int b = 0; b < 16; b++) { float val = y1[tid * 16 + b]; s1 += val; s2 += val * val; }
    float m = s1 * (1.f / 16), vr = s2 * (1.f / 16) - m * m;
    float scale = cg0[tid] * rsqrtf(vr + EPSV);
    float shift = cbe0[tid] - m * scale;
    for (int b = 0; b < 16; b++)
      y1[tid * 16 + b] = fmaxf(fmaf(y1[tid * 16 + b], scale, shift), 0.f);
  }
  __syncthreads();
  for (int j = tid; j < 3072; j += 256) {
    int o = j >> 4, b = j & 15;
    float acc = cb1[o];
    for (int c = 0; c < 100; c++) acc = fmaf(y1[c * 16 + b], cw1[o * 100 + c], acc);
    y2l[o * 16 + b] = acc;
  }
  __syncthreads();
  if (tid < 192) {
    float s1 = 0.f, s2 = 0.f;
    for (int b = 0; b < 16; b++) { float val = y2l[tid * 16 + b]; s1 += val; s2 += val * val; }
    float m = s1 * (1.f / 16), vr = s2 * (1.f / 16) - m * m;
    float scale = cg1[tid] * rsqrtf(vr + EPSV);
    float shift = cbe1[tid] - m * scale;
    for (int b = 0; b < 16; b++) {
      float r = fmaxf(fmaf(y2l[tid * 16 + b], scale, shift), 0.f);
      xg[b * 192 + tid]  = r;
      xgT[tid * 16 + b]  = r;
    }
  }
}

// ---------------- Phase B: fused dilated conv + gate + relu + Ww-dot + loss --------
__global__ __launch_bounds__(256) void conv_fuse(
    const float* __restrict__ x, const float* __restrict__ Wb,
    const float* __restrict__ bb, const float* __restrict__ Ww,
    const float* __restrict__ bw, const float* __restrict__ xg,
    float* __restrict__ out_loss)
{
  __shared__ __align__(16) float xs[25 * 264];   // [ci][8 + t], 8 zeros causal history
  __shared__ __align__(16) float wbl[75 * 48];   // [(ci*3+k)][m]
  __shared__ float wwl[25 * 193];                // Ww padded stride 193
  __shared__ float xgl[192];
  __shared__ float bbl[192];
  __shared__ float bwl[25];
  const int tid = threadIdx.x;
  const int wg = blockIdx.x;
  const int v = wg % 25, n = wg / 25;
  const int b = n / 3;

  for (int j = tid; j < 6400; j += 256) {
    int t = j / 25, ci = j - t * 25;
    xs[ci * 264 + 8 + t] = x[n * 6400 + j];
  }
  for (int j = tid; j < 200; j += 256) {
    int ci = j >> 3, q = j & 7;
    xs[ci * 264 + q] = 0.f;
  }
  for (int j = tid; j < 4800; j += 256) {
    int vv = j / 192, o = j - vv * 192;
    wwl[vv * 193 + o] = Ww[j];
  }
  for (int j = tid; j < 192; j += 256) {
    xgl[j] = xg[b * 192 + j];
    int i = j / 48, m = j - i * 48;
    bbl[j] = bb[(i * 25 + v) * 48 + m];
  }
  if (tid < 25) bwl[tid] = bw[tid];

  const int mq = tid & 3, tl = tid >> 2;
  int wwbase[4], tp_[4], vp_[4];
  #pragma unroll
  for (int tt = 0; tt < 4; tt++) {
    int flat = v * 256 + tl + 64 * tt;   // flat = v*T + t  ->  (t', v')
    tp_[tt] = flat / 25;
    vp_[tt] = flat - tp_[tt] * 25;
    wwbase[tt] = vp_[tt] * 193;
  }
  float accout[4] = {0.f, 0.f, 0.f, 0.f};

  for (int i = 0; i < 4; i++) {
    __syncthreads();
    const float* wsrc = Wb + (i * 25 + v) * 3600;
    for (int j = tid; j < 3600; j += 256) {
      int m = j / 75, q = j - m * 75;
      wbl[q * 48 + m] = wsrc[j];
    }
    __syncthreads();
    const int d = i + 1;
    float conv[12][4];
    #pragma unroll
    for (int mi = 0; mi < 12; mi++) {
      float bv = bbl[i * 48 + mq * 12 + mi];
      #pragma unroll
      for (int tt = 0; tt < 4; tt++) conv[mi][tt] = bv;
    }
    for (int ci = 0; ci < 25; ci++) {
      const float* xrow  = &xs[ci * 264 + 8 + tl];
      const float* wrow0 = &wbl[(ci * 3) * 48 + mq * 12];
      #pragma unroll
      for (int k = 0; k < 3; k++) {
        const int off = (k - 2) * d;
        const float4 wa  = *(const float4*)(wrow0 + k * 48);
        const float4 wb2 = *(const float4*)(wrow0 + k * 48 + 4);
        const float4 wc  = *(const float4*)(wrow0 + k * 48 + 8);
        const float wr[12] = {wa.x, wa.y, wa.z, wa.w,
                              wb2.x, wb2.y, wb2.z, wb2.w,
                              wc.x, wc.y, wc.z, wc.w};
        float xv[4];
        #pragma unroll
        for (int tt = 0; tt < 4; tt++) xv[tt] = xrow[64 * tt + off];
        #pragma unroll
        for (int mi = 0; mi < 12; mi++)
          #pragma unroll
          for (int tt = 0; tt < 4; tt++)
            conv[mi][tt] = fmaf(xv[tt], wr[mi], conv[mi][tt]);
      }
    }
    #pragma unroll
    for (int mi = 0; mi < 12; mi++) {
      const int o = i * 48 + mq * 12 + mi;
      const float gate = xgl[o];
      #pragma unroll
      for (int tt = 0; tt < 4; tt++) {
        float z = fmaxf(gate * conv[mi][tt], 0.f);
        accout[tt] = fmaf(z, wwl[wwbase[tt] + o], accout[tt]);
      }
    }
  }
  #pragma unroll
  for (int tt = 0; tt < 4; tt++) {
    float a = accout[tt];
    a += __shfl_xor(a, 1);
    a += __shfl_xor(a, 2);
    if (mq == 0 && tp_[tt] < 255) {
      float pf = a + bwl[vp_[tt]];
      float xn = x[n * 6400 + (tp_[tt] + 1) * 25 + vp_[tt]];
      float dd = pf - xn;
      out_loss[(n * 25 + vp_[tt]) * 255 + tp_[tt]] = dd * dd;
    }
  }
}

// ---------------- Phase C: gc max + group-lasso reg (625 blocks) ----------------
__global__ __launch_bounds__(64) void gc_reg_kernel(
    const float* __restrict__ Wb, const float* __restrict__ xgT,
    float* __restrict__ gc_out, float* __restrict__ reg_out)
{
  __shared__ float sW[576];        // [o=(i*48+m)][k]
  __shared__ float sG[192 * 17];   // [o][b], stride 17 (bank-spread)
  const int tid = threadIdx.x;
  const int v1 = blockIdx.x / 25, v2 = blockIdx.x % 25;
  for (int j = tid; j < 3072; j += 64) {
    int o = j >> 4, bq = j & 15;
    sG[o * 17 + bq] = xgT[j];
  }
  for (int p = tid; p < 192; p += 64) {
    int i = p / 48, m = p - i * 48;
    const float* src = Wb + ((i * 25 + v1) * 48 + m) * 75 + v2 * 3;
    sW[p * 3 + 0] = src[0]; sW[p * 3 + 1] = src[1]; sW[p * 3 + 2] = src[2];
  }
  __syncthreads();
  const int b = tid & 15, c = tid >> 4;   // c in 0..3 -> o-chunk
  float s0 = 0.f, s1 = 0.f, s2 = 0.f, mx = -3.0e38f;
  #pragma unroll 4
  for (int o = c * 48; o < c * 48 + 48; o++) {
    float g = sG[o * 17 + b];
    float a0 = sW[o * 3] * g, a1 = sW[o * 3 + 1] * g, a2 = sW[o * 3 + 2] * g;
    s0 = fmaf(a0, a0, s0);
    s1 = fmaf(a1, a1, s1);
    s2 = fmaf(a2, a2, s2);
    mx = fmaxf(mx, fmaxf(fmaxf(a0, a1), a2));
  }
  s0 += __shfl_xor(s0, 16); s0 += __shfl_xor(s0, 32);
  s1 += __shfl_xor(s1, 16); s1 += __shfl_xor(s1, 32);
  s2 += __shfl_xor(s2, 16); s2 += __shfl_xor(s2, 32);
  mx = fmaxf(mx, __shfl_xor(mx, 16)); mx = fmaxf(mx, __shfl_xor(mx, 32));
  float contrib = 0.f;
  if (c == 0) {
    gc_out[(b * 25 + v1) * 25 + v2] = mx;
    contrib = sqrtf(s0 + s1 + s2) + sqrtf(s0) + sqrtf(s1) + sqrtf(s2);
  }
  #pragma unroll
  for (int d = 1; d < 16; d <<= 1) contrib += __shfl_xor(contrib, d);
  if (tid == 0) atomicAdd(reg_out, 0.01f * contrib);
}

extern "C" void kernel_launch(void* const* d_in, const int* in_sizes, int n_in,
                              void* d_out, int out_size, void* d_ws, size_t ws_size,
                              hipStream_t stream)
{
  const float* x    = (const float*)d_in[0];
  const float* Wb   = (const float*)d_in[1];
  const float* bb   = (const float*)d_in[2];
  const float* fw0  = (const float*)d_in[3];
  const float* fb0  = (const float*)d_in[4];
  const float* fg0  = (const float*)d_in[5];
  const float* fbe0 = (const float*)d_in[6];
  const float* fw1  = (const float*)d_in[7];
  const float* fb1  = (const float*)d_in[8];
  const float* fg1  = (const float*)d_in[9];
  const float* fbe1 = (const float*)d_in[10];
  const float* fw2  = (const float*)d_in[11];
  const float* fb2  = (const float*)d_in[12];
  const float* fg2  = (const float*)d_in[13];
  const float* fbe2 = (const float*)d_in[14];
  const float* fw3  = (const float*)d_in[15];
  const float* fb3  = (const float*)d_in[16];
  const float* fg3  = (const float*)d_in[17];
  const float* fbe3 = (const float*)d_in[18];
  const float* cw0  = (const float*)d_in[19];
  const float* cb0  = (const float*)d_in[20];
  const float* cg0  = (const float*)d_in[21];
  const float* cbe0 = (const float*)d_in[22];
  const float* cw1  = (const float*)d_in[23];
  const float* cb1  = (const float*)d_in[24];
  const float* cg1  = (const float*)d_in[25];
  const float* cbe1 = (const float*)d_in[26];
  const float* Ww   = (const float*)d_in[27];
  const float* bw   = (const float*)d_in[28];

  float* ws  = (float*)d_ws;
  float* out = (float*)d_out;

  float* ST  = ws;            // st0[20] st1[200] st2[20] st3[2] = 242
  float* HP  = ws + 242;      // 400
  float* XG  = ws + 642;      // 3072 (b-major)
  float* XGT = XG + 3072;     // 3072 (o-major)

  hipMemsetAsync(ST, 0, 642 * sizeof(float), stream);          // stats + hp
  hipMemsetAsync(out + 316000, 0, sizeof(float), stream);      // reg scalar

  chain_kernel<1><<<400, 256, 0, stream>>>(x, fw0, fb0, fg0, fbe0, fw1, fb1, fg1, fbe1,
      fw2, fb2, fg2, fbe2, fw3, fb3, fg3, fbe3, ST, ST, nullptr);
  chain_kernel<2><<<400, 256, 0, stream>>>(x, fw0, fb0, fg0, fbe0, fw1, fb1, fg1, fbe1,
      fw2, fb2, fg2, fbe2, fw3, fb3, fg3, fbe3, ST, ST + 20, nullptr);
  chain_kernel<3><<<400, 256, 0, stream>>>(x, fw0, fb0, fg0, fbe0, fw1, fb1, fg1, fbe1,
      fw2, fb2, fg2, fbe2, fw3, fb3, fg3, fbe3, ST, ST + 220, nullptr);
  chain_kernel<4><<<400, 256, 0, stream>>>(x, fw0, fb0, fg0, fbe0, fw1, fb1, fg1, fbe1,
      fw2, fb2, fg2, fbe2, fw3, fb3, fg3, fbe3, ST, ST + 240, nullptr);
  chain_kernel<5><<<400, 256, 0, stream>>>(x, fw0, fb0, fg0, fbe0, fw1, fb1, fg1, fbe1,
      fw2, fb2, fg2, fbe2, fw3, fb3, fg3, fbe3, ST, nullptr, HP);
  head_kernel<<<1, 256, 0, stream>>>(HP, cw0, cb0, cg0, cbe0, cw1, cb1, cg1, cbe1, XG, XGT);
  conv_fuse<<<1200, 256, 0, stream>>>(x, Wb, bb, Ww, bw, XG, out);
  gc_reg_kernel<<<625, 64, 0, stream>>>(Wb, XGT, out + 306000, out + 316000);
}

// Round 5
// 202.028 us; speedup vs baseline: 3.1955x; 1.4821x over previous
//
#include <hip/hip_runtime.h>

#define EPSV 1e-5f

constexpr int kB = 16, kC = 3, kT = 256, kV = 25;
constexpr int kMID = 48, kNB = 4, kOUT = 192, kN = 48;
constexpr int kS  = kB * kT * kV;   // 102400 sites (b,t,v)
constexpr int kTV = kT * kV;        // 6400

typedef __attribute__((ext_vector_type(8))) short bf16x8;
typedef __attribute__((ext_vector_type(4))) float f32x4;

__device__ __forceinline__ short f2bf(float f) {
  unsigned u = __float_as_uint(f);
  u += 0x7fffu + ((u >> 16) & 1u);          // RNE
  return (short)(u >> 16);
}
__device__ __forceinline__ float bf2f(short s) {
  return __uint_as_float(((unsigned)(unsigned short)s) << 16);
}

// ---------------- Phase A: recompute chain (register-streaming) ----------------

template<int NO>
__device__ __forceinline__ void stat_reduce_reg(const float (&y)[NO], float* statl,
                                                float* out_stats, int tid)
{
  #pragma unroll
  for (int o = 0; o < NO; o++) {
    float s1 = y[o], s2 = y[o] * y[o];
    #pragma unroll
    for (int d = 32; d > 0; d >>= 1) { s1 += __shfl_xor(s1, d); s2 += __shfl_xor(s2, d); }
    if ((tid & 63) == 0) { atomicAdd(&statl[2 * o], s1); atomicAdd(&statl[2 * o + 1], s2); }
  }
  __syncthreads();
  for (int j = tid; j < 2 * NO; j += 256) atomicAdd(&out_stats[j], statl[j]);
}

template<int DEPTH>
__global__ __launch_bounds__(256) void chain_kernel(
    const float* __restrict__ x,
    const float* __restrict__ fw0, const float* __restrict__ fb0,
    const float* __restrict__ fg0, const float* __restrict__ fbe0,
    const float* __restrict__ fw1, const float* __restrict__ fb1,
    const float* __restrict__ fg1, const float* __restrict__ fbe1,
    const float* __restrict__ fw2, const float* __restrict__ fb2,
    const float* __restrict__ fg2, const float* __restrict__ fbe2,
    const float* __restrict__ fw3, const float* __restrict__ fb3,
    const float* __restrict__ fg3, const float* __restrict__ fbe3,
    const float* __restrict__ ST,
    float* __restrict__ out_stats,
    float* __restrict__ hp)
{
  __shared__ __align__(16) float w0p[40];    // [o][4]: w,w,w,bias
  __shared__ __align__(16) float w1p[1200];  // [o][12]: 10 w, bias, pad
  __shared__ __align__(16) float w2t[1200];  // [c][12]: fw2 transposed, pad
  __shared__ __align__(16) float w3p[12];
  __shared__ float b2s[10];
  __shared__ float sc0[10], sh0[10], sc1[100], sh1[100], sc2[10], sh2[10];
  __shared__ float sc3s, sh3s;
  __shared__ float statl[200];
  __shared__ float poolp[25];
  const int tid = threadIdx.x;

  for (int j = tid; j < 40; j += 256) {
    int o = j >> 2, c = j & 3;
    w0p[j] = (c < 3) ? fw0[o * 3 + c] : fb0[o];
  }
  if constexpr (DEPTH >= 2) {
    for (int j = tid; j < 1200; j += 256) {
      int o = j / 12, c = j - o * 12;
      w1p[j] = (c < 10) ? fw1[o * 10 + c] : (c == 10 ? fb1[o] : 0.f);
    }
    if (tid < 10) {
      float m = ST[2 * tid] * (1.f / kS);
      float vr = ST[2 * tid + 1] * (1.f / kS) - m * m;
      float s = fg0[tid] * rsqrtf(vr + EPSV);
      sc0[tid] = s; sh0[tid] = fbe0[tid] - m * s;
    }
  }
  if constexpr (DEPTH >= 3) {
    for (int j = tid; j < 1000; j += 256) {
      int jj = j / 100, c = j - jj * 100;
      w2t[c * 12 + jj] = fw2[j];
    }
    for (int c = tid; c < 100; c += 256) { w2t[c * 12 + 10] = 0.f; w2t[c * 12 + 11] = 0.f; }
    if (tid < 10) b2s[tid] = fb2[tid];
    if (tid < 100) {
      const float* st1 = ST + 20;
      float m = st1[2 * tid] * (1.f / kS);
      float vr = st1[2 * tid + 1] * (1.f / kS) - m * m;
      float s = fg1[tid] * rsqrtf(vr + EPSV);
      sc1[tid] = s; sh1[tid] = fbe1[tid] - m * s;
    }
  }
  if constexpr (DEPTH >= 4) {
    if (tid < 12) w3p[tid] = (tid < 10) ? fw3[tid] : (tid == 10 ? fb3[0] : 0.f);
    if (tid < 10) {
      const float* st2 = ST + 220;
      float m = st2[2 * tid] * (1.f / kS);
      float vr = st2[2 * tid + 1] * (1.f / kS) - m * m;
      float s = fg2[tid] * rsqrtf(vr + EPSV);
      sc2[tid] = s; sh2[tid] = fbe2[tid] - m * s;
    }
  }
  if constexpr (DEPTH >= 5) {
    if (tid == 0) {
      const float* st3 = ST + 240;
      float m = st3[0] * (1.f / kS);
      float vr = st3[1] * (1.f / kS) - m * m;
      float s = fg3[0] * rsqrtf(vr + EPSV);
      sc3s = s; sh3s = fbe3[0] - m * s;
    }
    if (tid < 25) poolp[tid] = 0.f;
  }
  if constexpr (DEPTH <= 4) {
    constexpr int NO = (DEPTH == 1) ? 10 : (DEPTH == 2) ? 100 : (DEPTH == 3) ? 10 : 1;
    for (int j = tid; j < 2 * NO; j += 256) statl[j] = 0.f;
  }
  __syncthreads();

  const int s = blockIdx.x * 256 + tid;
  const int b = s / kTV, r = s - b * kTV;

  const float xv0 = x[(b * 3 + 0) * kTV + r];
  const float xv1 = x[(b * 3 + 1) * kTV + r];
  const float xv2 = x[(b * 3 + 2) * kTV + r];
  float h0[10];
  #pragma unroll
  for (int o = 0; o < 10; o++) {
    const float4 w = *(const float4*)&w0p[o * 4];
    h0[o] = fmaf(xv0, w.x, fmaf(xv1, w.y, fmaf(xv2, w.z, w.w)));
  }
  if constexpr (DEPTH == 1) { stat_reduce_reg<10>(h0, statl, out_stats, tid); return; }

  #pragma unroll
  for (int o = 0; o < 10; o++) h0[o] = fmaxf(fmaf(h0[o], sc0[o], sh0[o]), 0.f);

  if constexpr (DEPTH == 2) {
    for (int o = 0; o < 100; o++) {
      const float4 wa = *(const float4*)&w1p[o * 12];
      const float4 wb = *(const float4*)&w1p[o * 12 + 4];
      const float4 wc = *(const float4*)&w1p[o * 12 + 8];
      float a = wc.z;
      a = fmaf(h0[0], wa.x, a); a = fmaf(h0[1], wa.y, a);
      a = fmaf(h0[2], wa.z, a); a = fmaf(h0[3], wa.w, a);
      a = fmaf(h0[4], wb.x, a); a = fmaf(h0[5], wb.y, a);
      a = fmaf(h0[6], wb.z, a); a = fmaf(h0[7], wb.w, a);
      a = fmaf(h0[8], wc.x, a); a = fmaf(h0[9], wc.y, a);
      float s1 = a, s2 = a * a;
      #pragma unroll
      for (int d = 32; d > 0; d >>= 1) { s1 += __shfl_xor(s1, d); s2 += __shfl_xor(s2, d); }
      if ((tid & 63) == 0) { atomicAdd(&statl[2 * o], s1); atomicAdd(&statl[2 * o + 1], s2); }
    }
    __syncthreads();
    for (int j = tid; j < 200; j += 256) atomicAdd(&out_stats[j], statl[j]);
    return;
  }

  float acc[10];
  #pragma unroll
  for (int j = 0; j < 10; j++) acc[j] = b2s[j];
  for (int o = 0; o < 100; o++) {
    const float4 wa = *(const float4*)&w1p[o * 12];
    const float4 wb = *(const float4*)&w1p[o * 12 + 4];
    const float4 wc = *(const float4*)&w1p[o * 12 + 8];
    float a = wc.z;
    a = fmaf(h0[0], wa.x, a); a = fmaf(h0[1], wa.y, a);
    a = fmaf(h0[2], wa.z, a); a = fmaf(h0[3], wa.w, a);
    a = fmaf(h0[4], wb.x, a); a = fmaf(h0[5], wb.y, a);
    a = fmaf(h0[6], wb.z, a); a = fmaf(h0[7], wb.w, a);
    a = fmaf(h0[8], wc.x, a); a = fmaf(h0[9], wc.y, a);
    float h1 = fmaxf(fmaf(a, sc1[o], sh1[o]), 0.f);
    const float4 va = *(const float4*)&w2t[o * 12];
    const float4 vb = *(const float4*)&w2t[o * 12 + 4];
    const float4 vc = *(const float4*)&w2t[o * 12 + 8];
    acc[0] = fmaf(h1, va.x, acc[0]); acc[1] = fmaf(h1, va.y, acc[1]);
    acc[2] = fmaf(h1, va.z, acc[2]); acc[3] = fmaf(h1, va.w, acc[3]);
    acc[4] = fmaf(h1, vb.x, acc[4]); acc[5] = fmaf(h1, vb.y, acc[5]);
    acc[6] = fmaf(h1, vb.z, acc[6]); acc[7] = fmaf(h1, vb.w, acc[7]);
    acc[8] = fmaf(h1, vc.x, acc[8]); acc[9] = fmaf(h1, vc.y, acc[9]);
  }
  if constexpr (DEPTH == 3) { stat_reduce_reg<10>(acc, statl, out_stats, tid); return; }

  #pragma unroll
  for (int o = 0; o < 10; o++) acc[o] = fmaxf(fmaf(acc[o], sc2[o], sh2[o]), 0.f);
  const float4 wa = *(const float4*)&w3p[0];
  const float4 wb = *(const float4*)&w3p[4];
  const float4 wc = *(const float4*)&w3p[8];
  float y3 = wc.z;
  y3 = fmaf(acc[0], wa.x, y3); y3 = fmaf(acc[1], wa.y, y3);
  y3 = fmaf(acc[2], wa.z, y3); y3 = fmaf(acc[3], wa.w, y3);
  y3 = fmaf(acc[4], wb.x, y3); y3 = fmaf(acc[5], wb.y, y3);
  y3 = fmaf(acc[6], wb.z, y3); y3 = fmaf(acc[7], wb.w, y3);
  y3 = fmaf(acc[8], wc.x, y3); y3 = fmaf(acc[9], wc.y, y3);
  if constexpr (DEPTH == 4) {
    float t1[1] = { y3 };
    stat_reduce_reg<1>(t1, statl, out_stats, tid);
    return;
  }

  if constexpr (DEPTH == 5) {
    float h3 = fmaxf(fmaf(y3, sc3s, sh3s), 0.f);
    const int v = r % 25;
    atomicAdd(&poolp[v], h3);
    __syncthreads();
    if (tid < 25) atomicAdd(&hp[b * 25 + tid], poolp[tid]);
  }
}

// tiny FC head: hp sums (16,25) -> 100 -> 192 with per-batch BN
__global__ __launch_bounds__(256) void head_kernel(
    const float* __restrict__ hp,
    const float* __restrict__ cw0, const float* __restrict__ cb0,
    const float* __restrict__ cg0, const float* __restrict__ cbe0,
    const float* __restrict__ cw1, const float* __restrict__ cb1,
    const float* __restrict__ cg1, const float* __restrict__ cbe1,
    float* __restrict__ xg, float* __restrict__ xgT)
{
  __shared__ float hpl[400];
  __shared__ float y1[100 * 16];
  __shared__ float y2l[192 * 16];
  const int tid = threadIdx.x;
  for (int j = tid; j < 400; j += 256) hpl[j] = hp[j] * (1.f / kT);
  __syncthreads();
  for (int j = tid; j < 1600; j += 256) {
    int o = j >> 4, b = j & 15;
    float acc = cb0[o];
    for (int v = 0; v < 25; v++) acc = fmaf(hpl[b * 25 + v], cw0[o * 25 + v], acc);
    y1[o * 16 + b] = acc;
  }
  __syncthreads();
  if (tid < 100) {
    float s1 = 0.f, s2 = 0.f;
    for (int b = 0; b < 16; b++) { float val = y1[tid * 16 + b]; s1 += val; s2 += val * val; }
    float m = s1 * (1.f / 16), vr = s2 * (1.f / 16) - m * m;
    float scale = cg0[tid] * rsqrtf(vr + EPSV);
    float shift = cbe0[tid] - m * scale;
    for (int b = 0; b < 16; b++)
      y1[tid * 16 + b] = fmaxf(fmaf(y1[tid * 16 + b], scale, shift), 0.f);
  }
  __syncthreads();
  for (int j = tid; j < 3072; j += 256) {
    int o = j >> 4, b = j & 15;
    float acc = cb1[o];
    for (int c = 0; c < 100; c++) acc = fmaf(y1[c * 16 + b], cw1[o * 100 + c], acc);
    y2l[o * 16 + b] = acc;
  }
  __syncthreads();
  if (tid < 192) {
    float s1 = 0.f, s2 = 0.f;
    for (int b = 0; b < 16; b++) { float val = y2l[tid * 16 + b]; s1 += val; s2 += val * val; }
    float m = s1 * (1.f / 16), vr = s2 * (1.f / 16) - m * m;
    float scale = cg1[tid] * rsqrtf(vr + EPSV);
    float shift = cbe1[tid] - m * scale;
    for (int b = 0; b < 16; b++) {
      float r = fmaxf(fmaf(y2l[tid * 16 + b], scale, shift), 0.f);
      xg[b * 192 + tid]  = r;
      xgT[tid * 16 + b]  = r;
    }
  }
}

// ---------------- Phase B: MFMA fused dilated conv + gate + relu + Ww-dot + loss ----
// Per (n,v): D[m=48][t=256] = W[48 x K] * X[K x 256] per dilation, K = tap*32 + ci
// (3 MFMA k-steps of 32 = the 3 taps; ci 25..31 zero-padded). B^T-fragments read
// DIRECTLY from t-major xs with a dilation-shifted row index (free im2col).
__global__ __launch_bounds__(256) void conv_fuse_mfma(
    const float* __restrict__ x, const float* __restrict__ Wb,
    const float* __restrict__ bb, const float* __restrict__ Ww,
    const float* __restrict__ bw, const float* __restrict__ xg,
    float* __restrict__ out_loss)
{
  __shared__ short xs[264 * 40];    // [8 hist + 256 t][40], bf16; stride 80B (20dw: 2-way banks)
  __shared__ short As[48 * 104];    // [m][kk pad 104], bf16, per-dil; stride 208B (52dw: 2-way)
  __shared__ short wwb[25 * 200];   // [v'][o pad 200] bf16; stride 400B (100dw: 2-way)
  __shared__ float bbl[192], xgl[192], bwl[32];

  const int tid = threadIdx.x;
  const int v = blockIdx.x % 25, n = blockIdx.x / 25;
  const int bidx = n / 3;

  {  // zero xs fully (history rows + ci pads) and As fully (kk pads persist)
    uint2* p = (uint2*)xs;
    for (int j = tid; j < 2640; j += 256) p[j] = make_uint2(0u, 0u);
    uint2* p2 = (uint2*)As;
    for (int j = tid; j < 1248; j += 256) p2[j] = make_uint2(0u, 0u);
  }
  __syncthreads();
  for (int j = tid; j < 6400; j += 256) {          // xs rows 8..263, cols 0..24
    int t = j / 25, ci = j - t * 25;
    xs[(8 + t) * 40 + ci] = f2bf(x[n * 6400 + j]);
  }
  for (int j = tid; j < 4800; j += 256) {          // ww -> bf16
    int vv = j / 192, o = j - vv * 192;
    wwb[vv * 200 + o] = f2bf(Ww[j]);
  }
  for (int j = tid; j < 192; j += 256) {
    xgl[j] = xg[bidx * 192 + j];
    int i = j / 48, m = j - i * 48;
    bbl[j] = bb[(i * 25 + v) * 48 + m];
  }
  if (tid < 25) bwl[tid] = bw[tid];

  const int lane = tid & 63, w = tid >> 6;
  const int c = lane & 15, q = lane >> 4;

  float accout[4] = {0.f, 0.f, 0.f, 0.f};
  int tarr[4], vparr[4];
  #pragma unroll
  for (int z = 0; z < 4; z++) {
    int t = (w * 4 + z) * 16 + c;
    tarr[z] = t;
    vparr[z] = (v * 256 + t) % 25;
  }

  for (int i = 0; i < 4; i++) {
    __syncthreads();                                // prev-dil readers done / initial stage done
    const float* wsrc = Wb + (i * 25 + v) * 3600;
    for (int j = tid; j < 3600; j += 256) {         // W[m][ci][k] -> As[m][k*32+ci]
      int m = j / 75, r = j - m * 75;
      int ci = r / 3, k = r - ci * 3;
      As[m * 104 + k * 32 + ci] = f2bf(wsrc[j]);
    }
    __syncthreads();

    const int d = i + 1;
    bf16x8 af[3][3];
    #pragma unroll
    for (int mt = 0; mt < 3; mt++)
      #pragma unroll
      for (int s = 0; s < 3; s++)
        af[mt][s] = *(const bf16x8*)&As[(mt * 16 + c) * 104 + s * 32 + q * 8];

    #pragma unroll
    for (int z = 0; z < 4; z++) {
      const int t = tarr[z];
      bf16x8 bf[3];
      #pragma unroll
      for (int s = 0; s < 3; s++) {
        int row = 8 + t + (s - 2) * d;              // taps at t-2d, t-d, t
        bf[s] = *(const bf16x8*)&xs[row * 40 + q * 8];
      }
      f32x4 acc[3] = {{0.f,0.f,0.f,0.f},{0.f,0.f,0.f,0.f},{0.f,0.f,0.f,0.f}};
      #pragma unroll
      for (int s = 0; s < 3; s++)
        #pragma unroll
        for (int mt = 0; mt < 3; mt++)
          acc[mt] = __builtin_amdgcn_mfma_f32_16x16x32_bf16(af[mt][s], bf[s], acc[mt], 0, 0, 0);
      const int vp = vparr[z];
      float aout = 0.f;
      #pragma unroll
      for (int mt = 0; mt < 3; mt++) {
        #pragma unroll
        for (int r = 0; r < 4; r++) {
          int o = i * 48 + mt * 16 + q * 4 + r;     // C/D: col=lane&15 (t), row=q*4+r (m)
          float val = acc[mt][r] + bbl[o];
          float zz = fmaxf(xgl[o] * val, 0.f);
          aout = fmaf(zz, bf2f(wwb[vp * 200 + o]), aout);
        }
      }
      accout[z] += aout;
    }
  }

  #pragma unroll
  for (int z = 0; z < 4; z++) {
    float a = accout[z];
    a += __shfl_xor(a, 16);
    a += __shfl_xor(a, 32);
    if (q == 0) {
      int flat = v * 256 + tarr[z];
      int tp = flat / 25, vp = flat - tp * 25;
      if (tp < 255) {
        float pf = a + bwl[vp];
        float xn = x[n * 6400 + (tp + 1) * 25 + vp];
        float dd = pf - xn;
        out_loss[(n * 25 + vp) * 255 + tp] = dd * dd;
      }
    }
  }
}

// ---------------- Phase C: gc max + group-lasso reg (625 blocks) ----------------
__global__ __launch_bounds__(64) void gc_reg_kernel(
    const float* __restrict__ Wb, const float* __restrict__ xgT,
    float* __restrict__ gc_out, float* __restrict__ reg_out)
{
  __shared__ float sW[576];        // [o=(i*48+m)][k]
  __shared__ float sG[192 * 17];   // [o][b], stride 17
  const int tid = threadIdx.x;
  const int v1 = blockIdx.x / 25, v2 = blockIdx.x % 25;
  for (int j = tid; j < 3072; j += 64) {
    int o = j >> 4, bq = j & 15;
    sG[o * 17 + bq] = xgT[j];
  }
  for (int p = tid; p < 192; p += 64) {
    int i = p / 48, m = p - i * 48;
    const float* src = Wb + ((i * 25 + v1) * 48 + m) * 75 + v2 * 3;
    sW[p * 3 + 0] = src[0]; sW[p * 3 + 1] = src[1]; sW[p * 3 + 2] = src[2];
  }
  __syncthreads();
  const int b = tid & 15, c = tid >> 4;
  float s0 = 0.f, s1 = 0.f, s2 = 0.f, mx = -3.0e38f;
  #pragma unroll 4
  for (int o = c * 48; o < c * 48 + 48; o++) {
    float g = sG[o * 17 + b];
    float a0 = sW[o * 3] * g, a1 = sW[o * 3 + 1] * g, a2 = sW[o * 3 + 2] * g;
    s0 = fmaf(a0, a0, s0);
    s1 = fmaf(a1, a1, s1);
    s2 = fmaf(a2, a2, s2);
    mx = fmaxf(mx, fmaxf(fmaxf(a0, a1), a2));
  }
  s0 += __shfl_xor(s0, 16); s0 += __shfl_xor(s0, 32);
  s1 += __shfl_xor(s1, 16); s1 += __shfl_xor(s1, 32);
  s2 += __shfl_xor(s2, 16); s2 += __shfl_xor(s2, 32);
  mx = fmaxf(mx, __shfl_xor(mx, 16)); mx = fmaxf(mx, __shfl_xor(mx, 32));
  float contrib = 0.f;
  if (c == 0) {
    gc_out[(b * 25 + v1) * 25 + v2] = mx;
    contrib = sqrtf(s0 + s1 + s2) + sqrtf(s0) + sqrtf(s1) + sqrtf(s2);
  }
  #pragma unroll
  for (int d = 1; d < 16; d <<= 1) contrib += __shfl_xor(contrib, d);
  if (tid == 0) atomicAdd(reg_out, 0.01f * contrib);
}

extern "C" void kernel_launch(void* const* d_in, const int* in_sizes, int n_in,
                              void* d_out, int out_size, void* d_ws, size_t ws_size,
                              hipStream_t stream)
{
  const float* x    = (const float*)d_in[0];
  const float* Wb   = (const float*)d_in[1];
  const float* bb   = (const float*)d_in[2];
  const float* fw0  = (const float*)d_in[3];
  const float* fb0  = (const float*)d_in[4];
  const float* fg0  = (const float*)d_in[5];
  const float* fbe0 = (const float*)d_in[6];
  const float* fw1  = (const float*)d_in[7];
  const float* fb1  = (const float*)d_in[8];
  const float* fg1  = (const float*)d_in[9];
  const float* fbe1 = (const float*)d_in[10];
  const float* fw2  = (const float*)d_in[11];
  const float* fb2  = (const float*)d_in[12];
  const float* fg2  = (const float*)d_in[13];
  const float* fbe2 = (const float*)d_in[14];
  const float* fw3  = (const float*)d_in[15];
  const float* fb3  = (const float*)d_in[16];
  const float* fg3  = (const float*)d_in[17];
  const float* fbe3 = (const float*)d_in[18];
  const float* cw0  = (const float*)d_in[19];
  const float* cb0  = (const float*)d_in[20];
  const float* cg0  = (const float*)d_in[21];
  const float* cbe0 = (const float*)d_in[22];
  const float* cw1  = (const float*)d_in[23];
  const float* cb1  = (const float*)d_in[24];
  const float* cg1  = (const float*)d_in[25];
  const float* cbe1 = (const float*)d_in[26];
  const float* Ww   = (const float*)d_in[27];
  const float* bw   = (const float*)d_in[28];

  float* ws  = (float*)d_ws;
  float* out = (float*)d_out;

  float* ST  = ws;            // st0[20] st1[200] st2[20] st3[2] = 242
  float* HP  = ws + 242;      // 400
  float* XG  = ws + 642;      // 3072 (b-major)
  float* XGT = XG + 3072;     // 3072 (o-major)

  hipMemsetAsync(ST, 0, 642 * sizeof(float), stream);
  hipMemsetAsync(out + 316000, 0, sizeof(float), stream);

  chain_kernel<1><<<400, 256, 0, stream>>>(x, fw0, fb0, fg0, fbe0, fw1, fb1, fg1, fbe1,
      fw2, fb2, fg2, fbe2, fw3, fb3, fg3, fbe3, ST, ST, nullptr);
  chain_kernel<2><<<400, 256, 0, stream>>>(x, fw0, fb0, fg0, fbe0, fw1, fb1, fg1, fbe1,
      fw2, fb2, fg2, fbe2, fw3, fb3, fg3, fbe3, ST, ST + 20, nullptr);
  chain_kernel<3><<<400, 256, 0, stream>>>(x, fw0, fb0, fg0, fbe0, fw1, fb1, fg1, fbe1,
      fw2, fb2, fg2, fbe2, fw3, fb3, fg3, fbe3, ST, ST + 220, nullptr);
  chain_kernel<4><<<400, 256, 0, stream>>>(x, fw0, fb0, fg0, fbe0, fw1, fb1, fg1, fbe1,
      fw2, fb2, fg2, fbe2, fw3, fb3, fg3, fbe3, ST, ST + 240, nullptr);
  chain_kernel<5><<<400, 256, 0, stream>>>(x, fw0, fb0, fg0, fbe0, fw1, fb1, fg1, fbe1,
      fw2, fb2, fg2, fbe2, fw3, fb3, fg3, fbe3, ST, nullptr, HP);
  head_kernel<<<1, 256, 0, stream>>>(HP, cw0, cb0, cg0, cbe0, cw1, cb1, cg1, cbe1, XG, XGT);
  conv_fuse_mfma<<<1200, 256, 0, stream>>>(x, Wb, bb, Ww, bw, XG, out);
  gc_reg_kernel<<<625, 64, 0, stream>>>(Wb, XGT, out + 306000, out + 316000);
}

// Round 6
// 165.237 us; speedup vs baseline: 3.9071x; 1.2227x over previous
//
#include <hip/hip_runtime.h>

#define EPSV 1e-5f

constexpr int kB = 16, kC = 3, kT = 256, kV = 25;
constexpr int kMID = 48, kNB = 4, kOUT = 192, kN = 48;
constexpr int kS  = kB * kT * kV;   // 102400 sites
constexpr int kTV = kT * kV;        // 6400

typedef __attribute__((ext_vector_type(8))) short bf16x8;
typedef __attribute__((ext_vector_type(4))) float f32x4;

__device__ __forceinline__ short f2bf(float f) {
  unsigned u = __float_as_uint(f);
  u += 0x7fffu + ((u >> 16) & 1u);          // RNE
  return (short)(u >> 16);
}
__device__ __forceinline__ float bf2f(short s) {
  return __uint_as_float(((unsigned)(unsigned short)s) << 16);
}
__device__ __forceinline__ float wred(float v) {
  #pragma unroll
  for (int d = 32; d > 0; d >>= 1) v += __shfl_xor(v, d);
  return v;
}

// ---------------- P1: x moments (M1[3], M2 upper-tri[6]) ----------------
__global__ __launch_bounds__(128) void xmom_kernel(const float* __restrict__ x,
                                                   float* __restrict__ xmom)
{
  __shared__ float red[9];
  const int tid = threadIdx.x;
  if (tid < 9) red[tid] = 0.f;
  __syncthreads();
  const int s = blockIdx.x * 128 + tid;
  const int b = s / kTV, r = s - b * kTV;
  const float x0 = x[(b * 3 + 0) * kTV + r];
  const float x1 = x[(b * 3 + 1) * kTV + r];
  const float x2 = x[(b * 3 + 2) * kTV + r];
  const float p[9] = {x0, x1, x2, x0*x0, x0*x1, x0*x2, x1*x1, x1*x2, x2*x2};
  #pragma unroll
  for (int k = 0; k < 9; k++) {
    float t = wred(p[k]);
    if ((tid & 63) == 0) atomicAdd(&red[k], t);
  }
  __syncthreads();
  if (tid < 9) atomicAdd(&xmom[tid], red[tid]);
}

// analytic st0 (scale/shift of bn0) from x moments -- inline snippet used by P2, P3
__device__ __forceinline__ void st0_from_xmom(int o, const float* fw0, const float* fb0,
                                              const float* fg0, const float* fbe0,
                                              const float* xmom, float* sc0, float* sh0)
{
  float w0 = fw0[o * 3], w1 = fw0[o * 3 + 1], w2 = fw0[o * 3 + 2], b = fb0[o];
  float Sw = w0 * xmom[0] + w1 * xmom[1] + w2 * xmom[2];
  float Q  = w0*w0*xmom[3] + w1*w1*xmom[6] + w2*w2*xmom[8]
           + 2.f*(w0*w1*xmom[4] + w0*w2*xmom[5] + w1*w2*xmom[7]);
  float mean = (Sw + (float)kS * b) * (1.f / kS);
  float e2   = (Q + 2.f * b * Sw) * (1.f / kS) + b * b;
  float var  = e2 - mean * mean;
  float sc   = fg0[o] * rsqrtf(var + EPSV);
  sc0[o] = sc; sh0[o] = fbe0[o] - mean * sc;
}

// ---------------- P2: h0 moments (S1[10] + M2 upper-tri[55]) ----------------
__global__ __launch_bounds__(128) void h0mom_kernel(
    const float* __restrict__ x,
    const float* __restrict__ fw0, const float* __restrict__ fb0,
    const float* __restrict__ fg0, const float* __restrict__ fbe0,
    const float* __restrict__ xmom, float* __restrict__ h0mom)
{
  __shared__ __align__(16) float w0p[40];
  __shared__ float sc0[10], sh0[10];
  __shared__ float red[65];
  const int tid = threadIdx.x;
  for (int j = tid; j < 40; j += 128) {
    int o = j >> 2, c = j & 3;
    w0p[j] = (c < 3) ? fw0[o * 3 + c] : fb0[o];
  }
  if (tid < 10) st0_from_xmom(tid, fw0, fb0, fg0, fbe0, xmom, sc0, sh0);
  if (tid < 65) red[tid] = 0.f;
  __syncthreads();
  const int s = blockIdx.x * 128 + tid;
  const int b = s / kTV, r = s - b * kTV;
  const float x0 = x[(b * 3 + 0) * kTV + r];
  const float x1 = x[(b * 3 + 1) * kTV + r];
  const float x2 = x[(b * 3 + 2) * kTV + r];
  float h0[10];
  #pragma unroll
  for (int o = 0; o < 10; o++) {
    const float4 w = *(const float4*)&w0p[o * 4];
    float y = fmaf(x0, w.x, fmaf(x1, w.y, fmaf(x2, w.z, w.w)));
    h0[o] = fmaxf(fmaf(y, sc0[o], sh0[o]), 0.f);
  }
  int idx = 0;
  #pragma unroll
  for (int c = 0; c < 10; c++) {
    float t = wred(h0[c]);
    if ((tid & 63) == 0) atomicAdd(&red[idx], t);
    idx++;
  }
  #pragma unroll
  for (int c = 0; c < 10; c++)
    #pragma unroll
    for (int cp = c; cp < 10; cp++) {
      float t = wred(h0[c] * h0[cp]);
      if ((tid & 63) == 0) atomicAdd(&red[idx], t);
      idx++;
    }
  __syncthreads();
  if (tid < 65) atomicAdd(&h0mom[tid], red[tid]);
}

// ---------------- P3: y2 pass (only 100-wide stream; writes y2 + st2) ----------------
__global__ __launch_bounds__(128) void y2_kernel(
    const float* __restrict__ x,
    const float* __restrict__ fw0, const float* __restrict__ fb0,
    const float* __restrict__ fg0, const float* __restrict__ fbe0,
    const float* __restrict__ fw1, const float* __restrict__ fb1,
    const float* __restrict__ fg1, const float* __restrict__ fbe1,
    const float* __restrict__ fw2, const float* __restrict__ fb2,
    const float* __restrict__ xmom, const float* __restrict__ h0mom,
    short* __restrict__ y2out, float* __restrict__ st2out)
{
  __shared__ __align__(16) float w0p[40];
  __shared__ __align__(16) float w1p[1200];  // [o][12]: 10 w, bias, pad
  __shared__ __align__(16) float w2t[1200];  // [c][12]: fw2 transposed, pad
  __shared__ float b2s[10];
  __shared__ float sc0[10], sh0[10], sc1[100], sh1[100];
  __shared__ float red[20];
  const int tid = threadIdx.x;

  for (int j = tid; j < 40; j += 128) {
    int o = j >> 2, c = j & 3;
    w0p[j] = (c < 3) ? fw0[o * 3 + c] : fb0[o];
  }
  for (int j = tid; j < 1200; j += 128) {
    int o = j / 12, c = j - o * 12;
    w1p[j] = (c < 10) ? fw1[o * 10 + c] : (c == 10 ? fb1[o] : 0.f);
  }
  for (int j = tid; j < 1000; j += 128) {
    int jj = j / 100, c = j - jj * 100;
    w2t[c * 12 + jj] = fw2[j];
  }
  for (int c = tid; c < 100; c += 128) { w2t[c * 12 + 10] = 0.f; w2t[c * 12 + 11] = 0.f; }
  if (tid < 10) {
    b2s[tid] = fb2[tid];
    st0_from_xmom(tid, fw0, fb0, fg0, fbe0, xmom, sc0, sh0);
  }
  if (tid < 20) red[tid] = 0.f;
  __syncthreads();                       // w1p ready
  if (tid < 100) {                       // st1 analytic from h0 moments
    float wr[10]; float S = 0.f, Q = 0.f;
    #pragma unroll
    for (int c = 0; c < 10; c++) { wr[c] = w1p[tid * 12 + c]; S = fmaf(wr[c], h0mom[c], S); }
    int idx = 10;
    #pragma unroll
    for (int c = 0; c < 10; c++) {
      Q = fmaf(wr[c] * wr[c], h0mom[idx], Q); idx++;
      #pragma unroll
      for (int cp = c + 1; cp < 10; cp++) { Q = fmaf(2.f * wr[c] * wr[cp], h0mom[idx], Q); idx++; }
    }
    float b = w1p[tid * 12 + 10];
    float mean = (S + (float)kS * b) * (1.f / kS);
    float e2   = (Q + 2.f * b * S) * (1.f / kS) + b * b;
    float var  = e2 - mean * mean;
    float sc   = fg1[tid] * rsqrtf(var + EPSV);
    sc1[tid] = sc; sh1[tid] = fbe1[tid] - mean * sc;
  }
  __syncthreads();

  const int s0 = blockIdx.x * 512 + tid;   // sites s0 + {0,128,256,384}
  float h0a[4][10];
  #pragma unroll
  for (int k = 0; k < 4; k++) {
    const int s = s0 + k * 128;
    const int b = s / kTV, r = s - b * kTV;
    const float x0 = x[(b * 3 + 0) * kTV + r];
    const float x1 = x[(b * 3 + 1) * kTV + r];
    const float x2 = x[(b * 3 + 2) * kTV + r];
    #pragma unroll
    for (int o = 0; o < 10; o++) {
      const float4 w = *(const float4*)&w0p[o * 4];
      float y = fmaf(x0, w.x, fmaf(x1, w.y, fmaf(x2, w.z, w.w)));
      h0a[k][o] = fmaxf(fmaf(y, sc0[o], sh0[o]), 0.f);
    }
  }
  float acc[4][10];
  #pragma unroll
  for (int k = 0; k < 4; k++)
    #pragma unroll
    for (int o = 0; o < 10; o++) acc[k][o] = b2s[o];

  #pragma unroll 2
  for (int o = 0; o < 100; o++) {
    const float4 wa = *(const float4*)&w1p[o * 12];
    const float4 wb = *(const float4*)&w1p[o * 12 + 4];
    const float4 wc = *(const float4*)&w1p[o * 12 + 8];
    const float4 va = *(const float4*)&w2t[o * 12];
    const float4 vb = *(const float4*)&w2t[o * 12 + 4];
    const float4 vc = *(const float4*)&w2t[o * 12 + 8];
    const float sc = sc1[o], sh = sh1[o];
    #pragma unroll
    for (int k = 0; k < 4; k++) {
      float a = wc.z;
      a = fmaf(h0a[k][0], wa.x, a); a = fmaf(h0a[k][1], wa.y, a);
      a = fmaf(h0a[k][2], wa.z, a); a = fmaf(h0a[k][3], wa.w, a);
      a = fmaf(h0a[k][4], wb.x, a); a = fmaf(h0a[k][5], wb.y, a);
      a = fmaf(h0a[k][6], wb.z, a); a = fmaf(h0a[k][7], wb.w, a);
      a = fmaf(h0a[k][8], wc.x, a); a = fmaf(h0a[k][9], wc.y, a);
      const float h1 = fmaxf(fmaf(a, sc, sh), 0.f);
      acc[k][0] = fmaf(h1, va.x, acc[k][0]); acc[k][1] = fmaf(h1, va.y, acc[k][1]);
      acc[k][2] = fmaf(h1, va.z, acc[k][2]); acc[k][3] = fmaf(h1, va.w, acc[k][3]);
      acc[k][4] = fmaf(h1, vb.x, acc[k][4]); acc[k][5] = fmaf(h1, vb.y, acc[k][5]);
      acc[k][6] = fmaf(h1, vb.z, acc[k][6]); acc[k][7] = fmaf(h1, vb.w, acc[k][7]);
      acc[k][8] = fmaf(h1, vc.x, acc[k][8]); acc[k][9] = fmaf(h1, vc.y, acc[k][9]);
    }
  }

  #pragma unroll
  for (int k = 0; k < 4; k++) {
    const int s = s0 + k * 128;
    #pragma unroll
    for (int o = 0; o < 10; o++) y2out[o * kS + s] = f2bf(acc[k][o]);
  }
  #pragma unroll
  for (int o = 0; o < 10; o++) {
    float s1 = acc[0][o] + acc[1][o] + acc[2][o] + acc[3][o];
    float s2 = acc[0][o]*acc[0][o] + acc[1][o]*acc[1][o] + acc[2][o]*acc[2][o] + acc[3][o]*acc[3][o];
    s1 = wred(s1); s2 = wred(s2);
    if ((tid & 63) == 0) { atomicAdd(&red[2 * o], s1); atomicAdd(&red[2 * o + 1], s2); }
  }
  __syncthreads();
  if (tid < 20) atomicAdd(&st2out[tid], red[tid]);
}

// ---------------- P4: y3 from y2 (memory-bound) ----------------
__global__ __launch_bounds__(128) void y3_kernel(
    const short* __restrict__ y2,
    const float* __restrict__ fw3, const float* __restrict__ fb3,
    const float* __restrict__ fg2, const float* __restrict__ fbe2,
    const float* __restrict__ st2,
    float* __restrict__ y3out, float* __restrict__ st3out)
{
  __shared__ float sc2[10], sh2[10], w3s[10];
  __shared__ float b3s;
  __shared__ float red[2];
  const int tid = threadIdx.x;
  if (tid < 10) {
    float m  = st2[2 * tid] * (1.f / kS);
    float vr = st2[2 * tid + 1] * (1.f / kS) - m * m;
    float sc = fg2[tid] * rsqrtf(vr + EPSV);
    sc2[tid] = sc; sh2[tid] = fbe2[tid] - m * sc;
    w3s[tid] = fw3[tid];
  }
  if (tid == 0) b3s = fb3[0];
  if (tid < 2) red[tid] = 0.f;
  __syncthreads();
  const int s = blockIdx.x * 128 + tid;
  float y3 = b3s;
  #pragma unroll
  for (int o = 0; o < 10; o++) {
    float v = bf2f(y2[o * kS + s]);
    float h2 = fmaxf(fmaf(v, sc2[o], sh2[o]), 0.f);
    y3 = fmaf(h2, w3s[o], y3);
  }
  y3out[s] = y3;
  float s1 = wred(y3), s2 = wred(y3 * y3);
  if ((tid & 63) == 0) { atomicAdd(&red[0], s1); atomicAdd(&red[1], s2); }
  __syncthreads();
  if (tid < 2) atomicAdd(&st3out[tid], red[tid]);
}

// ---------------- P5: bn3 + relu + T-pool ----------------
__global__ __launch_bounds__(128) void pool5_kernel(
    const float* __restrict__ y3,
    const float* __restrict__ fg3, const float* __restrict__ fbe3,
    const float* __restrict__ st3, float* __restrict__ hp)
{
  __shared__ float scsh[2];
  __shared__ float poolp[25];
  const int tid = threadIdx.x;
  if (tid == 0) {
    float m  = st3[0] * (1.f / kS);
    float vr = st3[1] * (1.f / kS) - m * m;
    float sc = fg3[0] * rsqrtf(vr + EPSV);
    scsh[0] = sc; scsh[1] = fbe3[0] - m * sc;
  }
  if (tid < 25) poolp[tid] = 0.f;
  __syncthreads();
  const int s = blockIdx.x * 128 + tid;
  const int b = s / kTV, r = s - b * kTV;
  const int v = r % 25;
  float h3 = fmaxf(fmaf(y3[s], scsh[0], scsh[1]), 0.f);
  atomicAdd(&poolp[v], h3);
  __syncthreads();
  if (tid < 25) atomicAdd(&hp[b * 25 + tid], poolp[tid]);
}

// ---------------- head: hp (16,25) -> 100 -> 192 with per-batch BN ----------------
__global__ __launch_bounds__(256) void head_kernel(
    const float* __restrict__ hp,
    const float* __restrict__ cw0, const float* __restrict__ cb0,
    const float* __restrict__ cg0, const float* __restrict__ cbe0,
    const float* __restrict__ cw1, const float* __restrict__ cb1,
    const float* __restrict__ cg1, const float* __restrict__ cbe1,
    float* __restrict__ xg, float* __restrict__ xgT)
{
  __shared__ float hpl[400];
  __shared__ float y1[100 * 16];
  __shared__ float y2l[192 * 16];
  const int tid = threadIdx.x;
  for (int j = tid; j < 400; j += 256) hpl[j] = hp[j] * (1.f / kT);
  __syncthreads();
  for (int j = tid; j < 1600; j += 256) {
    int o = j >> 4, b = j & 15;
    float acc = cb0[o];
    for (int v = 0; v < 25; v++) acc = fmaf(hpl[b * 25 + v], cw0[o * 25 + v], acc);
    y1[o * 16 + b] = acc;
  }
  __syncthreads();
  if (tid < 100) {
    float s1 = 0.f, s2 = 0.f;
    for (int b = 0; b < 16; b++) { float val = y1[tid * 16 + b]; s1 += val; s2 += val * val; }
    float m = s1 * (1.f / 16), vr = s2 * (1.f / 16) - m * m;
    float scale = cg0[tid] * rsqrtf(vr + EPSV);
    float shift = cbe0[tid] - m * scale;
    for (int b = 0; b < 16; b++)
      y1[tid * 16 + b] = fmaxf(fmaf(y1[tid * 16 + b], scale, shift), 0.f);
  }
  __syncthreads();
  for (int j = tid; j < 3072; j += 256) {
    int o = j >> 4, b = j & 15;
    float acc = cb1[o];
    for (int c = 0; c < 100; c++) acc = fmaf(y1[c * 16 + b], cw1[o * 100 + c], acc);
    y2l[o * 16 + b] = acc;
  }
  __syncthreads();
  if (tid < 192) {
    float s1 = 0.f, s2 = 0.f;
    for (int b = 0; b < 16; b++) { float val = y2l[tid * 16 + b]; s1 += val; s2 += val * val; }
    float m = s1 * (1.f / 16), vr = s2 * (1.f / 16) - m * m;
    float scale = cg1[tid] * rsqrtf(vr + EPSV);
    float shift = cbe1[tid] - m * scale;
    for (int b = 0; b < 16; b++) {
      float r = fmaxf(fmaf(y2l[tid * 16 + b], scale, shift), 0.f);
      xg[b * 192 + tid]  = r;
      xgT[tid * 16 + b]  = r;
    }
  }
}

// ---------------- Phase B: MFMA fused dilated conv + gate + relu + Ww-dot + loss ----
__global__ __launch_bounds__(256) void conv_fuse_mfma(
    const float* __restrict__ x, const float* __restrict__ Wb,
    const float* __restrict__ bb, const float* __restrict__ Ww,
    const float* __restrict__ bw, const float* __restrict__ xg,
    float* __restrict__ out_loss)
{
  __shared__ short xs[264 * 40];    // [8 hist + 256 t][40], bf16
  __shared__ short As[48 * 104];    // [m][kk pad 104], bf16, per-dil
  __shared__ float gw[25 * 200];    // gate-premultiplied Ww, f32, stride 200
  __shared__ float bbl[192], bwl[32];

  const int tid = threadIdx.x;
  const int v = blockIdx.x % 25, n = blockIdx.x / 25;
  const int bidx = n / 3;

  {  // zero xs fully (history rows + ci pads) and As fully (kk pads persist)
    uint2* p = (uint2*)xs;
    for (int j = tid; j < 2640; j += 256) p[j] = make_uint2(0u, 0u);
    uint2* p2 = (uint2*)As;
    for (int j = tid; j < 1248; j += 256) p2[j] = make_uint2(0u, 0u);
  }
  __syncthreads();
  for (int j = tid; j < 6400; j += 256) {
    int t = j / 25, ci = j - t * 25;
    xs[(8 + t) * 40 + ci] = f2bf(x[n * 6400 + j]);
  }
  for (int j = tid; j < 4800; j += 256) {          // gw = xg * Ww (xg >= 0)
    int vv = j / 192, o = j - vv * 192;
    gw[vv * 200 + o] = xg[bidx * 192 + o] * Ww[j];
  }
  for (int j = tid; j < 192; j += 256) {
    int i = j / 48, m = j - i * 48;
    bbl[j] = bb[(i * 25 + v) * 48 + m];
  }
  if (tid < 25) bwl[tid] = bw[tid];

  const int lane = tid & 63, w = tid >> 6;
  const int c = lane & 15, q = lane >> 4;

  float accout[4] = {0.f, 0.f, 0.f, 0.f};
  int tarr[4], vparr[4];
  #pragma unroll
  for (int z = 0; z < 4; z++) {
    int t = (w * 4 + z) * 16 + c;
    tarr[z] = t;
    vparr[z] = (v * 256 + t) % 25;
  }

  for (int i = 0; i < 4; i++) {
    __syncthreads();
    const float* wsrc = Wb + (i * 25 + v) * 3600;
    for (int j = tid; j < 3600; j += 256) {         // W[m][ci][k] -> As[m][k*32+ci]
      int m = j / 75, r = j - m * 75;
      int ci = r / 3, k = r - ci * 3;
      As[m * 104 + k * 32 + ci] = f2bf(wsrc[j]);
    }
    __syncthreads();

    const int d = i + 1;
    bf16x8 af[3][3];
    #pragma unroll
    for (int mt = 0; mt < 3; mt++)
      #pragma unroll
      for (int s = 0; s < 3; s++)
        af[mt][s] = *(const bf16x8*)&As[(mt * 16 + c) * 104 + s * 32 + q * 8];

    #pragma unroll
    for (int z = 0; z < 4; z++) {
      const int t = tarr[z];
      bf16x8 bf[3];
      #pragma unroll
      for (int s = 0; s < 3; s++) {
        int row = 8 + t + (s - 2) * d;              // taps at t-2d, t-d, t
        bf[s] = *(const bf16x8*)&xs[row * 40 + q * 8];
      }
      f32x4 acc[3] = {{0.f,0.f,0.f,0.f},{0.f,0.f,0.f,0.f},{0.f,0.f,0.f,0.f}};
      #pragma unroll
      for (int s = 0; s < 3; s++)
        #pragma unroll
        for (int mt = 0; mt < 3; mt++)
          acc[mt] = __builtin_amdgcn_mfma_f32_16x16x32_bf16(af[mt][s], bf[s], acc[mt], 0, 0, 0);
      const int vp = vparr[z];
      float aout = 0.f;
      #pragma unroll
      for (int mt = 0; mt < 3; mt++) {
        #pragma unroll
        for (int r = 0; r < 4; r++) {
          int o = i * 48 + mt * 16 + q * 4 + r;     // C/D: col=lane&15 (t), row=q*4+r (m)
          float val = acc[mt][r] + bbl[o];
          aout = fmaf(fmaxf(val, 0.f), gw[vp * 200 + o], aout);
        }
      }
      accout[z] += aout;
    }
  }

  #pragma unroll
  for (int z = 0; z < 4; z++) {
    float a = accout[z];
    a += __shfl_xor(a, 16);
    a += __shfl_xor(a, 32);
    if (q == 0) {
      int flat = v * 256 + tarr[z];
      int tp = flat / 25, vp = flat - tp * 25;
      if (tp < 255) {
        float pf = a + bwl[vp];
        float xn = x[n * 6400 + (tp + 1) * 25 + vp];
        float dd = pf - xn;
        out_loss[(n * 25 + vp) * 255 + tp] = dd * dd;
      }
    }
  }
}

// ---------------- Phase C: gc max + group-lasso reg (625 blocks) ----------------
__global__ __launch_bounds__(64) void gc_reg_kernel(
    const float* __restrict__ Wb, const float* __restrict__ xgT,
    float* __restrict__ gc_out, float* __restrict__ reg_out)
{
  __shared__ float sW[576];        // [o=(i*48+m)][k]
  __shared__ float sG[192 * 17];   // [o][b], stride 17
  const int tid = threadIdx.x;
  const int v1 = blockIdx.x / 25, v2 = blockIdx.x % 25;
  for (int j = tid; j < 3072; j += 64) {
    int o = j >> 4, bq = j & 15;
    sG[o * 17 + bq] = xgT[j];
  }
  for (int p = tid; p < 192; p += 64) {
    int i = p / 48, m = p - i * 48;
    const float* src = Wb + ((i * 25 + v1) * 48 + m) * 75 + v2 * 3;
    sW[p * 3 + 0] = src[0]; sW[p * 3 + 1] = src[1]; sW[p * 3 + 2] = src[2];
  }
  __syncthreads();
  const int b = tid & 15, c = tid >> 4;
  float s0 = 0.f, s1 = 0.f, s2 = 0.f, mx = -3.0e38f;
  #pragma unroll 4
  for (int o = c * 48; o < c * 48 + 48; o++) {
    float g = sG[o * 17 + b];
    float a0 = sW[o * 3] * g, a1 = sW[o * 3 + 1] * g, a2 = sW[o * 3 + 2] * g;
    s0 = fmaf(a0, a0, s0);
    s1 = fmaf(a1, a1, s1);
    s2 = fmaf(a2, a2, s2);
    mx = fmaxf(mx, fmaxf(fmaxf(a0, a1), a2));
  }
  s0 += __shfl_xor(s0, 16); s0 += __shfl_xor(s0, 32);
  s1 += __shfl_xor(s1, 16); s1 += __shfl_xor(s1, 32);
  s2 += __shfl_xor(s2, 16); s2 += __shfl_xor(s2, 32);
  mx = fmaxf(mx, __shfl_xor(mx, 16)); mx = fmaxf(mx, __shfl_xor(mx, 32));
  float contrib = 0.f;
  if (c == 0) {
    gc_out[(b * 25 + v1) * 25 + v2] = mx;
    contrib = sqrtf(s0 + s1 + s2) + sqrtf(s0) + sqrtf(s1) + sqrtf(s2);
  }
  #pragma unroll
  for (int d = 1; d < 16; d <<= 1) contrib += __shfl_xor(contrib, d);
  if (tid == 0) atomicAdd(reg_out, 0.01f * contrib);
}

extern "C" void kernel_launch(void* const* d_in, const int* in_sizes, int n_in,
                              void* d_out, int out_size, void* d_ws, size_t ws_size,
                              hipStream_t stream)
{
  const float* x    = (const float*)d_in[0];
  const float* Wb   = (const float*)d_in[1];
  const float* bb   = (const float*)d_in[2];
  const float* fw0  = (const float*)d_in[3];
  const float* fb0  = (const float*)d_in[4];
  const float* fg0  = (const float*)d_in[5];
  const float* fbe0 = (const float*)d_in[6];
  const float* fw1  = (const float*)d_in[7];
  const float* fb1  = (const float*)d_in[8];
  const float* fg1  = (const float*)d_in[9];
  const float* fbe1 = (const float*)d_in[10];
  const float* fw2  = (const float*)d_in[11];
  const float* fb2  = (const float*)d_in[12];
  const float* fg2  = (const float*)d_in[13];
  const float* fbe2 = (const float*)d_in[14];
  const float* fw3  = (const float*)d_in[15];
  const float* fb3  = (const float*)d_in[16];
  const float* fg3  = (const float*)d_in[17];
  const float* fbe3 = (const float*)d_in[18];
  const float* cw0  = (const float*)d_in[19];
  const float* cb0  = (const float*)d_in[20];
  const float* cg0  = (const float*)d_in[21];
  const float* cbe0 = (const float*)d_in[22];
  const float* cw1  = (const float*)d_in[23];
  const float* cb1  = (const float*)d_in[24];
  const float* cg1  = (const float*)d_in[25];
  const float* cbe1 = (const float*)d_in[26];
  const float* Ww   = (const float*)d_in[27];
  const float* bw   = (const float*)d_in[28];

  float* ws  = (float*)d_ws;
  float* out = (float*)d_out;

  float* XMOM  = ws;            // 9
  float* H0MOM = ws + 16;       // 65
  float* ST2   = ws + 296;      // 20
  float* ST3   = ws + 316;      // 2
  float* HP    = ws + 320;      // 400
  float* XG    = ws + 768;      // 3072 (b-major)
  float* XGT   = ws + 3840;     // 3072 (o-major)
  short* Y2    = (short*)(ws + 8192);   // 10 * kS bf16 = 512000 floats
  float* Y3    = ws + 520192;   // kS floats

  hipMemsetAsync(ws, 0, 720 * sizeof(float), stream);          // moments + stats + HP
  hipMemsetAsync(out + 316000, 0, sizeof(float), stream);      // reg scalar

  xmom_kernel<<<800, 128, 0, stream>>>(x, XMOM);
  h0mom_kernel<<<800, 128, 0, stream>>>(x, fw0, fb0, fg0, fbe0, XMOM, H0MOM);
  y2_kernel<<<200, 128, 0, stream>>>(x, fw0, fb0, fg0, fbe0, fw1, fb1, fg1, fbe1,
      fw2, fb2, XMOM, H0MOM, Y2, ST2);
  y3_kernel<<<800, 128, 0, stream>>>(Y2, fw3, fb3, fg2, fbe2, ST2, Y3, ST3);
  pool5_kernel<<<800, 128, 0, stream>>>(Y3, fg3, fbe3, ST3, HP);
  head_kernel<<<1, 256, 0, stream>>>(HP, cw0, cb0, cg0, cbe0, cw1, cb1, cg1, cbe1, XG, XGT);
  conv_fuse_mfma<<<1200, 256, 0, stream>>>(x, Wb, bb, Ww, bw, XG, out);
  gc_reg_kernel<<<625, 64, 0, stream>>>(Wb, XGT, out + 306000, out + 316000);
}